// Round 2
// baseline (4641.703 us; speedup 1.0000x reference)
//
#include <hip/hip_runtime.h>
#include <cstdint>
#include <cstddef>

#define NCLS 32000
#define EMBD 512
#define HIDD 1024
#define BATCH 64
#define SEQL 256
#define NWG 256
#define K0 1536
#define K1 2048
#define K0P (K0 + 8)
#define K1P (K1 + 8)
#define BH (BATCH * HIDD)          // 65536 elements
#define HBYTES (BH * 2)            // 131072 bytes per h buffer

typedef __attribute__((ext_vector_type(8))) short short8;
typedef __attribute__((ext_vector_type(4))) float float4v;
typedef unsigned long long ull;

// ---- workspace layout (bytes) ----
// ctr dwords: [0]=gctr, [16]=gen, [17]=dead (watchdog), [32+x]=cnt (membership),
//             [48]=sctr, [56]=sgen, [64+16x]=xctr, [192+16x]=xgen
#define WS_CTR   0                           // 2048 B reserved
#define WS_H0G   2048                        // 2 buffers bf16 [b][k]
#define WS_H1G   (WS_H0G + 2*HBYTES)
#define WS_XEMB  (WS_H1G + 2*HBYTES)         // 256*64*512*2 = 16 MB

#define SMEM_BYTES ((16*K0P + 16*K1P)*2 + (8192 + 32 + 512 + 8)*4)

__device__ __forceinline__ unsigned short f2bf(float f) {
  union { float f; uint32_t u; } x; x.f = f;
  uint32_t r = x.u + 0x7FFFu + ((x.u >> 16) & 1u);
  return (unsigned short)(r >> 16);
}

__device__ __forceinline__ float sigm(float x) {
  return 1.0f / (1.0f + __expf(-x));
}

// flat monotonic barrier (startup only) with deadlock watchdog
__device__ __forceinline__ void gbar(unsigned* bar, unsigned* gen, unsigned* dead,
                                     unsigned target) {
  __syncthreads();
  if (threadIdx.x == 0) {
    unsigned prev = __hip_atomic_fetch_add(bar, 1u, __ATOMIC_RELAXED, __HIP_MEMORY_SCOPE_AGENT);
    if (prev == target * NWG - 1u) {
      __hip_atomic_store(gen, target, __ATOMIC_RELAXED, __HIP_MEMORY_SCOPE_AGENT);
    } else {
      unsigned spin = 0;
      while (__hip_atomic_load(gen, __ATOMIC_RELAXED, __HIP_MEMORY_SCOPE_AGENT) < target) {
        if (__hip_atomic_load(dead, __ATOMIC_RELAXED, __HIP_MEMORY_SCOPE_AGENT) != 0u) break;
        if (++spin > 2000000u) {
          __hip_atomic_store(dead, 1u, __ATOMIC_RELAXED, __HIP_MEMORY_SCOPE_AGENT);
          break;
        }
        __builtin_amdgcn_s_sleep(1);
      }
    }
  }
  __syncthreads();
}

// hierarchical monotonic barrier: per-XCD aggregation, ONE buffer_inv per XCD
// per phase (executed by the last arriver on that XCD before releasing peers).
// Watchdog: any spin exceeding ~4M iterations sets ctr[17]; all waiters bail.
__device__ __forceinline__ void hbar(unsigned* ctr, unsigned xcc, unsigned nloc,
                                     unsigned nxcd, unsigned tgt) {
  __syncthreads();   // drains vmcnt -> this WG's sc1 publishes are visible
  if (threadIdx.x == 0) {
    unsigned* xctr = ctr + 64 + 16 * xcc;
    unsigned* xgen = ctr + 192 + 16 * xcc;
    unsigned* dead = ctr + 17;
    unsigned a = __hip_atomic_fetch_add(xctr, 1u, __ATOMIC_RELAXED, __HIP_MEMORY_SCOPE_AGENT);
    if (a == tgt * nloc - 1u) {            // last arriver on this XCD
      unsigned g = __hip_atomic_fetch_add(ctr, 1u, __ATOMIC_RELAXED, __HIP_MEMORY_SCOPE_AGENT);
      if (g == tgt * nxcd - 1u) {          // last arriver globally
        __hip_atomic_store(ctr + 16, tgt, __ATOMIC_RELAXED, __HIP_MEMORY_SCOPE_AGENT);
      } else {
        unsigned spin = 0;
        while (__hip_atomic_load(ctr + 16, __ATOMIC_RELAXED, __HIP_MEMORY_SCOPE_AGENT) < tgt) {
          if (__hip_atomic_load(dead, __ATOMIC_RELAXED, __HIP_MEMORY_SCOPE_AGENT) != 0u) break;
          if (++spin > 4000000u) {
            __hip_atomic_store(dead, 1u, __ATOMIC_RELAXED, __HIP_MEMORY_SCOPE_AGENT);
            break;
          }
        }
      }
      asm volatile("buffer_inv sc1\n\ts_waitcnt vmcnt(0)" ::: "memory");
      __hip_atomic_store(xgen, tgt, __ATOMIC_RELAXED, __HIP_MEMORY_SCOPE_AGENT);
    } else {
      unsigned spin = 0;
      while (__hip_atomic_load(xgen, __ATOMIC_RELAXED, __HIP_MEMORY_SCOPE_AGENT) < tgt) {
        if (__hip_atomic_load(dead, __ATOMIC_RELAXED, __HIP_MEMORY_SCOPE_AGENT) != 0u) break;
        if (++spin > 4000000u) {
          __hip_atomic_store(dead, 1u, __ATOMIC_RELAXED, __HIP_MEMORY_SCOPE_AGENT);
          break;
        }
      }
    }
  }
  __syncthreads();
}

__global__ void init_bar_k(char* ws) {
  if (threadIdx.x < 320) ((unsigned*)(ws + WS_CTR))[threadIdx.x] = 0u;
}

// gather embeddings -> bf16 xemb[t][b][e]
__global__ void embed_k(const int* __restrict__ X, const float* __restrict__ Cemb,
                        char* __restrict__ ws) {
  uint32_t p = blockIdx.x * 256u + threadIdx.x;   // pair index, 256*64*256 = 4194304
  uint32_t t = p >> 14;
  uint32_t r = p & 16383u;
  uint32_t b = r >> 8;
  uint32_t e2 = r & 255u;
  int row = X[b * SEQL + t];
  const float2 v = *(const float2*)(Cemb + (size_t)row * EMBD + (size_t)e2 * 2);
  uint32_t lo = f2bf(v.x), hi = f2bf(v.y);
  ((uint32_t*)(ws + WS_XEMB))[p] = (hi << 16) | lo;
}

__global__ __launch_bounds__(512, 1)
void lstm_k(const float* __restrict__ Wi0, const float* __restrict__ Wc0,
            const float* __restrict__ Wf0, const float* __restrict__ Wo0,
            const float* __restrict__ Wi1, const float* __restrict__ Wc1,
            const float* __restrict__ Wf1, const float* __restrict__ Wo1,
            const float* __restrict__ bi0, const float* __restrict__ bc0,
            const float* __restrict__ bf0, const float* __restrict__ bo0,
            const float* __restrict__ bi1, const float* __restrict__ bc1,
            const float* __restrict__ bf1, const float* __restrict__ bo1,
            char* ws) {
  const int wg   = blockIdx.x;
  const int tid  = threadIdx.x;
  const int lane = tid & 63;
  const int wv   = tid >> 6;        // 0..7
  const int l15  = lane & 15;
  const int quad = lane >> 4;

  extern __shared__ char smem[];
  unsigned short* w0 = (unsigned short*)smem;        // [16][K0P] bf16
  unsigned short* w1 = w0 + 16 * K0P;                // [16][K1P] bf16
  float* red  = (float*)(w1 + 16 * K1P);             // [8 waves][64 b][16 n]
  float* bias = red + 8192;                          // [32]
  float* cst  = bias + 32;                           // [512]
  int*   meta = (int*)(cst + 512);                   // [0]=nloc, [1]=nxcd

  unsigned short* h0buf = (unsigned short*)(ws + WS_H0G);
  unsigned short* h1buf = (unsigned short*)(ws + WS_H1G);
  const unsigned short* xemb = (const unsigned short*)(ws + WS_XEMB);
  unsigned* ctr = (unsigned*)(ws + WS_CTR);

  // XCD id (HW_REG_XCC_ID = hwreg 20, offset 0, width 4) [measured: learn_hip m09]
  const unsigned xcc = __builtin_amdgcn_s_getreg((3u << 11) | 20u) & 7u;

  // register XCD membership
  if (tid == 0)
    __hip_atomic_fetch_add(ctr + 32 + xcc, 1u, __ATOMIC_RELAXED, __HIP_MEMORY_SCOPE_AGENT);

  // ---- stage weights into LDS as bf16, layout [n = jl*4+g][k contiguous] ----
  {
    const float* W0g[4] = {Wi0, Wc0, Wf0, Wo0};
    const float* W1g[4] = {Wi1, Wc1, Wf1, Wo1};
    int jl = tid & 3;
    int kr = tid >> 2;            // 0..127
    int jg = wg * 4 + jl;
    for (int g = 0; g < 4; ++g) {
      unsigned short* dst0 = w0 + (jl * 4 + g) * K0P;
      const float* s0 = W0g[g] + jg;
      for (int k = kr; k < K0; k += 128) dst0[k] = f2bf(s0[(size_t)k * HIDD]);
      unsigned short* dst1 = w1 + (jl * 4 + g) * K1P;
      const float* s1 = W1g[g] + jg;
      for (int k = kr; k < K1; k += 128) dst1[k] = f2bf(s1[(size_t)k * HIDD]);
    }
  }
  if (tid < 32) {
    const float* B0g[4] = {bi0, bc0, bf0, bo0};
    const float* B1g[4] = {bi1, bc1, bf1, bo1};
    int lay = tid >> 4, idx = tid & 15, jl = idx >> 2, g = idx & 3;
    bias[tid] = (lay ? B1g[g] : B0g[g])[wg * 4 + jl];
  }
  cst[tid] = 0.f;
  if (tid < 128) {   // zero h state (buffer 0) via agent-coherent stores
    unsigned short* base = (tid < 64) ? h0buf : h1buf;
    int b = tid & 63;
    __hip_atomic_store((ull*)(base + (size_t)b * HIDD + wg * 4), 0ull,
                       __ATOMIC_RELAXED, __HIP_MEMORY_SCOPE_AGENT);
  }

  gbar(ctr + 48, ctr + 56, ctr + 17, 1u);   // startup: membership final, h zeroed, weights staged

  if (tid == 0) {
    int nl = (int)__hip_atomic_load(ctr + 32 + xcc, __ATOMIC_RELAXED, __HIP_MEMORY_SCOPE_AGENT);
    int nx = 0;
    for (int x = 0; x < 8; ++x)
      nx += (__hip_atomic_load(ctr + 32 + x, __ATOMIC_RELAXED, __HIP_MEMORY_SCOPE_AGENT) != 0u);
    meta[0] = nl; meta[1] = nx;
  }
  __syncthreads();
  const unsigned nloc = (unsigned)meta[0], nxcd = (unsigned)meta[1];

  unsigned tgt = 0;
  // phase p: waves 0-3 run L0(step p), waves 4-7 run L1(step p-1), concurrently.
  for (int p = 0; p <= SEQL; ++p) {
    const int run0 = (p < SEQL);
    const int run1 = (p >= 1);
    if (wv < 4) {
      if (run0) {
        const unsigned short* hp = h0buf + (size_t)(p & 1) * BH;        // h0(p-1)
        const unsigned short* xe = xemb + (size_t)p * BATCH * EMBD;
        float4v acc0 = {0.f,0.f,0.f,0.f}, acc1 = acc0, acc2 = acc0, acc3 = acc0;
        const int kbeg = wv * 384;
        for (int i = 0; i < 12; ++i) {
          int k0 = kbeg + i * 32;
          short8 bfr = *(const short8*)(w0 + l15 * K0P + k0 + quad * 8);
          const unsigned short* as; int koff, stride;
          if (k0 < HIDD) { as = hp; koff = k0; stride = HIDD; }
          else           { as = xe; koff = k0 - HIDD; stride = EMBD; }
          const unsigned short* ab = as + koff + quad * 8 + (size_t)l15 * stride;
          short8 f0 = *(const short8*)(ab);
          short8 f1 = *(const short8*)(ab + 16 * stride);
          short8 f2 = *(const short8*)(ab + 32 * stride);
          short8 f3 = *(const short8*)(ab + 48 * stride);
          acc0 = __builtin_amdgcn_mfma_f32_16x16x32_bf16(f0, bfr, acc0, 0, 0, 0);
          acc1 = __builtin_amdgcn_mfma_f32_16x16x32_bf16(f1, bfr, acc1, 0, 0, 0);
          acc2 = __builtin_amdgcn_mfma_f32_16x16x32_bf16(f2, bfr, acc2, 0, 0, 0);
          acc3 = __builtin_amdgcn_mfma_f32_16x16x32_bf16(f3, bfr, acc3, 0, 0, 0);
        }
        float* rw = red + wv * 1024 + quad * 64 + l15;
        #pragma unroll
        for (int r = 0; r < 4; ++r) {
          rw[r * 16]       = acc0[r];
          rw[256 + r * 16] = acc1[r];
          rw[512 + r * 16] = acc2[r];
          rw[768 + r * 16] = acc3[r];
        }
      }
    } else {
      if (run1) {
        const unsigned short* h1p = h1buf + (size_t)((p & 1) ^ 1) * BH;  // h1(p-2)
        const unsigned short* h0c = h0buf + (size_t)(p & 1) * BH;        // h0(p-1)
        float4v acc0 = {0.f,0.f,0.f,0.f}, acc1 = acc0, acc2 = acc0, acc3 = acc0;
        const int kbeg = (wv - 4) * 512;
        for (int i = 0; i < 16; ++i) {
          int k0 = kbeg + i * 32;
          short8 bfr = *(const short8*)(w1 + l15 * K1P + k0 + quad * 8);
          const unsigned short* as; int koff;
          if (k0 < HIDD) { as = h1p; koff = k0; }
          else           { as = h0c; koff = k0 - HIDD; }
          const unsigned short* ab = as + koff + quad * 8 + (size_t)l15 * HIDD;
          short8 f0 = *(const short8*)(ab);
          short8 f1 = *(const short8*)(ab + 16 * HIDD);
          short8 f2 = *(const short8*)(ab + 32 * HIDD);
          short8 f3 = *(const short8*)(ab + 48 * HIDD);
          acc0 = __builtin_amdgcn_mfma_f32_16x16x32_bf16(f0, bfr, acc0, 0, 0, 0);
          acc1 = __builtin_amdgcn_mfma_f32_16x16x32_bf16(f1, bfr, acc1, 0, 0, 0);
          acc2 = __builtin_amdgcn_mfma_f32_16x16x32_bf16(f2, bfr, acc2, 0, 0, 0);
          acc3 = __builtin_amdgcn_mfma_f32_16x16x32_bf16(f3, bfr, acc3, 0, 0, 0);
        }
        float* rw = red + wv * 1024 + quad * 64 + l15;
        #pragma unroll
        for (int r = 0; r < 4; ++r) {
          rw[r * 16]       = acc0[r];
          rw[256 + r * 16] = acc1[r];
          rw[512 + r * 16] = acc2[r];
          rw[768 + r * 16] = acc3[r];
        }
      }
    }
    __syncthreads();
    // split epilogue: tid<256 -> L0 gates+publish, tid>=256 -> L1
    if (tid < 256) {
      if (run0) {
        int b = tid >> 2, jl = tid & 3;
        const float* rr = red + b * 16 + jl * 4;
        float4v v = *(const float4v*)rr;
        v += *(const float4v*)(rr + 1024);
        v += *(const float4v*)(rr + 2048);
        v += *(const float4v*)(rr + 3072);
        float ig = sigm(v.x + bias[jl * 4 + 0]);
        float gg = tanhf(v.y + bias[jl * 4 + 1]);
        float fg = sigm(v.z + bias[jl * 4 + 2]);
        float og = sigm(v.w + bias[jl * 4 + 3]);
        float c = fg * cst[tid] + ig * gg;
        cst[tid] = c;
        unsigned x  = f2bf(og * tanhf(c));
        unsigned x1 = (unsigned)__shfl((int)x, lane + 1);
        unsigned x2 = (unsigned)__shfl((int)x, lane + 2);
        unsigned x3 = (unsigned)__shfl((int)x, lane + 3);
        if ((lane & 3) == 0) {
          ull val = (ull)(x | (x1 << 16)) | ((ull)(x2 | (x3 << 16)) << 32);
          unsigned short* dst = h0buf + (size_t)((p & 1) ^ 1) * BH + (size_t)b * HIDD + wg * 4;
          __hip_atomic_store((ull*)dst, val, __ATOMIC_RELAXED, __HIP_MEMORY_SCOPE_AGENT);
        }
      }
    } else {
      if (run1) {
        int t = tid - 256, b = t >> 2, jl = t & 3;
        const float* rr = red + 4096 + b * 16 + jl * 4;
        float4v v = *(const float4v*)rr;
        v += *(const float4v*)(rr + 1024);
        v += *(const float4v*)(rr + 2048);
        v += *(const float4v*)(rr + 3072);
        float ig = sigm(v.x + bias[16 + jl * 4 + 0]);
        float gg = tanhf(v.y + bias[16 + jl * 4 + 1]);
        float fg = sigm(v.z + bias[16 + jl * 4 + 2]);
        float og = sigm(v.w + bias[16 + jl * 4 + 3]);
        float c = fg * cst[tid] + ig * gg;
        cst[tid] = c;
        unsigned x  = f2bf(og * tanhf(c));
        unsigned x1 = (unsigned)__shfl((int)x, lane + 1);
        unsigned x2 = (unsigned)__shfl((int)x, lane + 2);
        unsigned x3 = (unsigned)__shfl((int)x, lane + 3);
        if ((lane & 3) == 0) {
          ull val = (ull)(x | (x1 << 16)) | ((ull)(x2 | (x3 << 16)) << 32);
          unsigned short* dst = h1buf + (size_t)(p & 1) * BH + (size_t)b * HIDD + wg * 4;
          __hip_atomic_store((ull*)dst, val, __ATOMIC_RELAXED, __HIP_MEMORY_SCOPE_AGENT);
        }
      }
    }
    if (p == SEQL) break;          // final h1(255) published (buf 0); done
    hbar(ctr, xcc, nloc, nxcd, ++tgt);
  }
}

// logits via MFMA: out[b][n] = sum_k h1[b][k] * Wout[k][n] + bout[n]
__global__ __launch_bounds__(256, 1)
void out_gemm_k(const char* __restrict__ ws, const float* __restrict__ Wout,
                const float* __restrict__ bout, float* __restrict__ out) {
  const unsigned short* h1 = (const unsigned short*)(ws + WS_H1G);  // bf16 [64][1024], buf 0
  const int tid = threadIdx.x, lane = tid & 63, wv = tid >> 6;
  const int l15 = lane & 15, quad = lane >> 4;
  const int n0 = blockIdx.x * 128 + wv * 32;
  float4v acc[4][2];
  #pragma unroll
  for (int m = 0; m < 4; ++m)
    #pragma unroll
    for (int f = 0; f < 2; ++f) acc[m][f] = (float4v){0.f, 0.f, 0.f, 0.f};

  for (int k0 = 0; k0 < HIDD; k0 += 32) {
    short8 a[4];
    #pragma unroll
    for (int m = 0; m < 4; ++m)
      a[m] = *(const short8*)(h1 + (size_t)(l15 + 16 * m) * HIDD + k0 + quad * 8);
    short8 bf[2];
    #pragma unroll
    for (int f = 0; f < 2; ++f) {
      int n = n0 + f * 16 + l15;
      #pragma unroll
      for (int j = 0; j < 8; ++j) {
        float w = Wout[(size_t)(k0 + quad * 8 + j) * NCLS + n];
        bf[f][j] = (short)f2bf(w);
      }
    }
    #pragma unroll
    for (int m = 0; m < 4; ++m)
      #pragma unroll
      for (int f = 0; f < 2; ++f)
        acc[m][f] = __builtin_amdgcn_mfma_f32_16x16x32_bf16(a[m], bf[f], acc[m][f], 0, 0, 0);
  }
  #pragma unroll
  for (int m = 0; m < 4; ++m)
    #pragma unroll
    for (int f = 0; f < 2; ++f) {
      int n = n0 + f * 16 + l15;
      float bb = bout[n];
      #pragma unroll
      for (int r = 0; r < 4; ++r) {
        int b = m * 16 + quad * 4 + r;
        out[(size_t)b * NCLS + n] = acc[m][f][r] + bb;
      }
    }
}

extern "C" void kernel_launch(void* const* d_in, const int* in_sizes, int n_in,
                              void* d_out, int out_size, void* d_ws, size_t ws_size,
                              hipStream_t stream) {
  const int*   X    = (const int*)d_in[0];
  const float* Cemb = (const float*)d_in[1];
  const float* Wi0  = (const float*)d_in[2];
  const float* bi0  = (const float*)d_in[3];
  const float* Wc0  = (const float*)d_in[4];
  const float* bc0  = (const float*)d_in[5];
  const float* Wf0  = (const float*)d_in[6];
  const float* bf0  = (const float*)d_in[7];
  const float* Wo0  = (const float*)d_in[8];
  const float* bo0  = (const float*)d_in[9];
  const float* Wi1  = (const float*)d_in[10];
  const float* bi1  = (const float*)d_in[11];
  const float* Wc1  = (const float*)d_in[12];
  const float* bc1  = (const float*)d_in[13];
  const float* Wf1  = (const float*)d_in[14];
  const float* bf1  = (const float*)d_in[15];
  const float* Wo1  = (const float*)d_in[16];
  const float* bo1  = (const float*)d_in[17];
  const float* Wout = (const float*)d_in[18];
  const float* bout = (const float*)d_in[19];
  float* out = (float*)d_out;
  char* ws = (char*)d_ws;

  hipFuncSetAttribute((const void*)lstm_k,
                      hipFuncAttributeMaxDynamicSharedMemorySize, SMEM_BYTES);

  init_bar_k<<<1, 512, 0, stream>>>(ws);
  embed_k<<<16384, 256, 0, stream>>>(X, Cemb, ws);
  lstm_k<<<NWG, 512, SMEM_BYTES, stream>>>(Wi0, Wc0, Wf0, Wo0, Wi1, Wc1, Wf1, Wo1,
                                           bi0, bc0, bf0, bo0, bi1, bc1, bf1, bo1, ws);
  out_gemm_k<<<250, 256, 0, stream>>>(ws, Wout, bout, out);
}

// Round 3
// 4436.168 us; speedup vs baseline: 1.0463x; 1.0463x over previous
//
#include <hip/hip_runtime.h>
#include <cstdint>
#include <cstddef>

#define NCLS 32000
#define EMBD 512
#define HIDD 1024
#define BATCH 64
#define SEQL 256
#define NWG 256
#define K0 1536
#define K1 2048
#define K0P (K0 + 8)
#define K1P (K1 + 8)
#define BH (BATCH * HIDD)          // 65536 elements
#define HBYTES (BH * 2)            // 131072 bytes per h buffer

typedef __attribute__((ext_vector_type(8))) short short8;
typedef __attribute__((ext_vector_type(4))) float float4v;
typedef unsigned long long ull;

// ---- workspace layout (bytes) ----
// ctr dwords: [0]=gctr, [16]=gen, [17]=dead (watchdog), [32+x]=cnt (membership),
//             [48]=sctr, [56]=sgen, [64+16x]=xctr, [192+16x]=xgen
#define WS_CTR   0                           // 2048 B reserved
#define WS_H0G   2048                        // 2 buffers bf16 [b][k]
#define WS_H1G   (WS_H0G + 2*HBYTES)
#define WS_XEMB  (WS_H1G + 2*HBYTES)         // 256*64*512*2 = 16 MB

#define SMEM_BYTES ((16*K0P + 16*K1P)*2 + (8192 + 32 + 512 + 8)*4)

__device__ __forceinline__ unsigned short f2bf(float f) {
  union { float f; uint32_t u; } x; x.f = f;
  uint32_t r = x.u + 0x7FFFu + ((x.u >> 16) & 1u);
  return (unsigned short)(r >> 16);
}

__device__ __forceinline__ float sigm(float x) {
  return 1.0f / (1.0f + __expf(-x));
}

// flat monotonic barrier (startup only) with deadlock watchdog
__device__ __forceinline__ void gbar(unsigned* bar, unsigned* gen, unsigned* dead,
                                     unsigned target) {
  __syncthreads();
  if (threadIdx.x == 0) {
    unsigned prev = __hip_atomic_fetch_add(bar, 1u, __ATOMIC_RELAXED, __HIP_MEMORY_SCOPE_AGENT);
    if (prev == target * NWG - 1u) {
      __hip_atomic_store(gen, target, __ATOMIC_RELAXED, __HIP_MEMORY_SCOPE_AGENT);
    } else {
      unsigned spin = 0;
      while (__hip_atomic_load(gen, __ATOMIC_RELAXED, __HIP_MEMORY_SCOPE_AGENT) < target) {
        if (__hip_atomic_load(dead, __ATOMIC_RELAXED, __HIP_MEMORY_SCOPE_AGENT) != 0u) break;
        if (++spin > 2000000u) {
          __hip_atomic_store(dead, 1u, __ATOMIC_RELAXED, __HIP_MEMORY_SCOPE_AGENT);
          break;
        }
        __builtin_amdgcn_s_sleep(1);
      }
    }
  }
  __syncthreads();
}

// hierarchical monotonic barrier: per-XCD aggregation. buffer_inv is issued by
// the XCD-last-arriver BEFORE the global release wait: all local publishes
// precede local arrivals (program order), and no agent on this XCD loads the
// next-phase read buffers between inv and release, so invalidating early is
// safe and the inv overlaps the global fan-in instead of serializing after it.
__device__ __forceinline__ void hbar(unsigned* ctr, unsigned xcc, unsigned nloc,
                                     unsigned nxcd, unsigned tgt) {
  __syncthreads();   // drains vmcnt -> this WG's sc1 publishes are visible
  if (threadIdx.x == 0) {
    unsigned* xctr = ctr + 64 + 16 * xcc;
    unsigned* xgen = ctr + 192 + 16 * xcc;
    unsigned* dead = ctr + 17;
    unsigned a = __hip_atomic_fetch_add(xctr, 1u, __ATOMIC_RELAXED, __HIP_MEMORY_SCOPE_AGENT);
    if (a == tgt * nloc - 1u) {            // last arriver on this XCD
      asm volatile("buffer_inv sc1\n\ts_waitcnt vmcnt(0)" ::: "memory");
      unsigned g = __hip_atomic_fetch_add(ctr, 1u, __ATOMIC_RELAXED, __HIP_MEMORY_SCOPE_AGENT);
      if (g == tgt * nxcd - 1u) {          // last arriver globally
        __hip_atomic_store(ctr + 16, tgt, __ATOMIC_RELAXED, __HIP_MEMORY_SCOPE_AGENT);
      } else {
        unsigned spin = 0;
        while (__hip_atomic_load(ctr + 16, __ATOMIC_RELAXED, __HIP_MEMORY_SCOPE_AGENT) < tgt) {
          if ((++spin & 63u) == 0u) {
            if (__hip_atomic_load(dead, __ATOMIC_RELAXED, __HIP_MEMORY_SCOPE_AGENT) != 0u) break;
            if (spin > 4000000u) {
              __hip_atomic_store(dead, 1u, __ATOMIC_RELAXED, __HIP_MEMORY_SCOPE_AGENT);
              break;
            }
          }
        }
      }
      __hip_atomic_store(xgen, tgt, __ATOMIC_RELAXED, __HIP_MEMORY_SCOPE_AGENT);
    } else {
      unsigned spin = 0;
      while (__hip_atomic_load(xgen, __ATOMIC_RELAXED, __HIP_MEMORY_SCOPE_AGENT) < tgt) {
        if ((++spin & 63u) == 0u) {
          if (__hip_atomic_load(dead, __ATOMIC_RELAXED, __HIP_MEMORY_SCOPE_AGENT) != 0u) break;
          if (spin > 4000000u) {
            __hip_atomic_store(dead, 1u, __ATOMIC_RELAXED, __HIP_MEMORY_SCOPE_AGENT);
            break;
          }
        }
      }
    }
  }
  __syncthreads();
}

__global__ void init_bar_k(char* ws) {
  if (threadIdx.x < 320) ((unsigned*)(ws + WS_CTR))[threadIdx.x] = 0u;
}

// gather embeddings -> bf16 xemb[t][b][e]
__global__ void embed_k(const int* __restrict__ X, const float* __restrict__ Cemb,
                        char* __restrict__ ws) {
  uint32_t p = blockIdx.x * 256u + threadIdx.x;   // pair index, 256*64*256 = 4194304
  uint32_t t = p >> 14;
  uint32_t r = p & 16383u;
  uint32_t b = r >> 8;
  uint32_t e2 = r & 255u;
  int row = X[b * SEQL + t];
  const float2 v = *(const float2*)(Cemb + (size_t)row * EMBD + (size_t)e2 * 2);
  uint32_t lo = f2bf(v.x), hi = f2bf(v.y);
  ((uint32_t*)(ws + WS_XEMB))[p] = (hi << 16) | lo;
}

__global__ __launch_bounds__(512, 1)
void lstm_k(const float* __restrict__ Wi0, const float* __restrict__ Wc0,
            const float* __restrict__ Wf0, const float* __restrict__ Wo0,
            const float* __restrict__ Wi1, const float* __restrict__ Wc1,
            const float* __restrict__ Wf1, const float* __restrict__ Wo1,
            const float* __restrict__ bi0, const float* __restrict__ bc0,
            const float* __restrict__ bf0, const float* __restrict__ bo0,
            const float* __restrict__ bi1, const float* __restrict__ bc1,
            const float* __restrict__ bf1, const float* __restrict__ bo1,
            char* ws) {
  const int wg   = blockIdx.x;
  const int tid  = threadIdx.x;
  const int lane = tid & 63;
  const int wv   = tid >> 6;        // 0..7
  const int l15  = lane & 15;
  const int quad = lane >> 4;

  extern __shared__ char smem[];
  unsigned short* w0 = (unsigned short*)smem;        // [16][K0P] bf16
  unsigned short* w1 = w0 + 16 * K0P;                // [16][K1P] bf16
  float* red  = (float*)(w1 + 16 * K1P);             // [8 waves][64 b][16 n]
  float* bias = red + 8192;                          // [32]
  float* cst  = bias + 32;                           // [512]
  int*   meta = (int*)(cst + 512);                   // [0]=nloc, [1]=nxcd

  unsigned short* h0buf = (unsigned short*)(ws + WS_H0G);
  unsigned short* h1buf = (unsigned short*)(ws + WS_H1G);
  const unsigned short* xemb = (const unsigned short*)(ws + WS_XEMB);
  unsigned* ctr = (unsigned*)(ws + WS_CTR);

  // XCD id (HW_REG_XCC_ID = hwreg 20, offset 0, width 4) [measured: learn_hip m09]
  const unsigned xcc = __builtin_amdgcn_s_getreg((3u << 11) | 20u) & 7u;

  // register XCD membership
  if (tid == 0)
    __hip_atomic_fetch_add(ctr + 32 + xcc, 1u, __ATOMIC_RELAXED, __HIP_MEMORY_SCOPE_AGENT);

  // ---- stage weights into LDS as bf16, layout [n = jl*4+g][k contiguous] ----
  {
    const float* W0g[4] = {Wi0, Wc0, Wf0, Wo0};
    const float* W1g[4] = {Wi1, Wc1, Wf1, Wo1};
    int jl = tid & 3;
    int kr = tid >> 2;            // 0..127
    int jg = wg * 4 + jl;
    for (int g = 0; g < 4; ++g) {
      unsigned short* dst0 = w0 + (jl * 4 + g) * K0P;
      const float* s0 = W0g[g] + jg;
      for (int k = kr; k < K0; k += 128) dst0[k] = f2bf(s0[(size_t)k * HIDD]);
      unsigned short* dst1 = w1 + (jl * 4 + g) * K1P;
      const float* s1 = W1g[g] + jg;
      for (int k = kr; k < K1; k += 128) dst1[k] = f2bf(s1[(size_t)k * HIDD]);
    }
  }
  if (tid < 32) {
    const float* B0g[4] = {bi0, bc0, bf0, bo0};
    const float* B1g[4] = {bi1, bc1, bf1, bo1};
    int lay = tid >> 4, idx = tid & 15, jl = idx >> 2, g = idx & 3;
    bias[tid] = (lay ? B1g[g] : B0g[g])[wg * 4 + jl];
  }
  cst[tid] = 0.f;
  if (tid < 128) {   // zero h state (buffer 0) via agent-coherent stores
    unsigned short* base = (tid < 64) ? h0buf : h1buf;
    int b = tid & 63;
    __hip_atomic_store((ull*)(base + (size_t)b * HIDD + wg * 4), 0ull,
                       __ATOMIC_RELAXED, __HIP_MEMORY_SCOPE_AGENT);
  }

  gbar(ctr + 48, ctr + 56, ctr + 17, 1u);   // startup: membership final, h zeroed, weights staged

  if (tid == 0) {
    int nl = (int)__hip_atomic_load(ctr + 32 + xcc, __ATOMIC_RELAXED, __HIP_MEMORY_SCOPE_AGENT);
    int nx = 0;
    for (int x = 0; x < 8; ++x)
      nx += (__hip_atomic_load(ctr + 32 + x, __ATOMIC_RELAXED, __HIP_MEMORY_SCOPE_AGENT) != 0u);
    meta[0] = nl; meta[1] = nx;
  }
  __syncthreads();
  const unsigned nloc = (unsigned)meta[0], nxcd = (unsigned)meta[1];

  unsigned tgt = 0;
  // phase p: waves 0-3 run L0(step p), waves 4-7 run L1(step p-1), concurrently.
  for (int p = 0; p <= SEQL; ++p) {
    const int run0 = (p < SEQL);
    const int run1 = (p >= 1);
    if (wv < 4) {
      if (run0) {
        const unsigned short* hp = h0buf + (size_t)(p & 1) * BH;        // h0(p-1)
        const unsigned short* xe = xemb + (size_t)p * BATCH * EMBD;
        float4v acc0 = {0.f,0.f,0.f,0.f}, acc1 = acc0, acc2 = acc0, acc3 = acc0;
        const int kbeg = wv * 384;
        // depth-2 prefetch: keep next iteration's 4 global loads in flight
        short8 c0, c1, c2, c3;
        {
          const unsigned short* ab; int st;
          if (kbeg < HIDD) { ab = hp + kbeg + quad * 8 + (size_t)l15 * HIDD; st = HIDD; }
          else             { ab = xe + (kbeg - HIDD) + quad * 8 + (size_t)l15 * EMBD; st = EMBD; }
          c0 = *(const short8*)(ab);
          c1 = *(const short8*)(ab + 16 * st);
          c2 = *(const short8*)(ab + 32 * st);
          c3 = *(const short8*)(ab + 48 * st);
        }
        #pragma unroll
        for (int i = 0; i < 12; ++i) {
          int k0 = kbeg + i * 32;
          short8 n0, n1, n2, n3;
          if (i < 11) {
            int kn = k0 + 32;
            const unsigned short* ab; int st;
            if (kn < HIDD) { ab = hp + kn + quad * 8 + (size_t)l15 * HIDD; st = HIDD; }
            else           { ab = xe + (kn - HIDD) + quad * 8 + (size_t)l15 * EMBD; st = EMBD; }
            n0 = *(const short8*)(ab);
            n1 = *(const short8*)(ab + 16 * st);
            n2 = *(const short8*)(ab + 32 * st);
            n3 = *(const short8*)(ab + 48 * st);
          }
          short8 bfr = *(const short8*)(w0 + l15 * K0P + k0 + quad * 8);
          acc0 = __builtin_amdgcn_mfma_f32_16x16x32_bf16(c0, bfr, acc0, 0, 0, 0);
          acc1 = __builtin_amdgcn_mfma_f32_16x16x32_bf16(c1, bfr, acc1, 0, 0, 0);
          acc2 = __builtin_amdgcn_mfma_f32_16x16x32_bf16(c2, bfr, acc2, 0, 0, 0);
          acc3 = __builtin_amdgcn_mfma_f32_16x16x32_bf16(c3, bfr, acc3, 0, 0, 0);
          c0 = n0; c1 = n1; c2 = n2; c3 = n3;
        }
        float* rw = red + wv * 1024 + quad * 64 + l15;
        #pragma unroll
        for (int r = 0; r < 4; ++r) {
          rw[r * 16]       = acc0[r];
          rw[256 + r * 16] = acc1[r];
          rw[512 + r * 16] = acc2[r];
          rw[768 + r * 16] = acc3[r];
        }
      }
    } else {
      if (run1) {
        const unsigned short* h1p = h1buf + (size_t)((p & 1) ^ 1) * BH;  // h1(p-2)
        const unsigned short* h0c = h0buf + (size_t)(p & 1) * BH;        // h0(p-1)
        float4v acc0 = {0.f,0.f,0.f,0.f}, acc1 = acc0, acc2 = acc0, acc3 = acc0;
        const int kbeg = (wv - 4) * 512;
        short8 c0, c1, c2, c3;
        {
          const unsigned short* ab =
            ((kbeg < HIDD) ? (h1p + kbeg) : (h0c + (kbeg - HIDD))) + quad * 8 + (size_t)l15 * HIDD;
          c0 = *(const short8*)(ab);
          c1 = *(const short8*)(ab + 16 * HIDD);
          c2 = *(const short8*)(ab + 32 * HIDD);
          c3 = *(const short8*)(ab + 48 * HIDD);
        }
        #pragma unroll
        for (int i = 0; i < 16; ++i) {
          int k0 = kbeg + i * 32;
          short8 n0, n1, n2, n3;
          if (i < 15) {
            int kn = k0 + 32;
            const unsigned short* ab =
              ((kn < HIDD) ? (h1p + kn) : (h0c + (kn - HIDD))) + quad * 8 + (size_t)l15 * HIDD;
            n0 = *(const short8*)(ab);
            n1 = *(const short8*)(ab + 16 * HIDD);
            n2 = *(const short8*)(ab + 32 * HIDD);
            n3 = *(const short8*)(ab + 48 * HIDD);
          }
          short8 bfr = *(const short8*)(w1 + l15 * K1P + k0 + quad * 8);
          acc0 = __builtin_amdgcn_mfma_f32_16x16x32_bf16(c0, bfr, acc0, 0, 0, 0);
          acc1 = __builtin_amdgcn_mfma_f32_16x16x32_bf16(c1, bfr, acc1, 0, 0, 0);
          acc2 = __builtin_amdgcn_mfma_f32_16x16x32_bf16(c2, bfr, acc2, 0, 0, 0);
          acc3 = __builtin_amdgcn_mfma_f32_16x16x32_bf16(c3, bfr, acc3, 0, 0, 0);
          c0 = n0; c1 = n1; c2 = n2; c3 = n3;
        }
        float* rw = red + wv * 1024 + quad * 64 + l15;
        #pragma unroll
        for (int r = 0; r < 4; ++r) {
          rw[r * 16]       = acc0[r];
          rw[256 + r * 16] = acc1[r];
          rw[512 + r * 16] = acc2[r];
          rw[768 + r * 16] = acc3[r];
        }
      }
    }
    __syncthreads();
    // split epilogue: tid<256 -> L0 gates+publish, tid>=256 -> L1
    if (tid < 256) {
      if (run0) {
        int b = tid >> 2, jl = tid & 3;
        const float* rr = red + b * 16 + jl * 4;
        float4v v = *(const float4v*)rr;
        v += *(const float4v*)(rr + 1024);
        v += *(const float4v*)(rr + 2048);
        v += *(const float4v*)(rr + 3072);
        float ig = sigm(v.x + bias[jl * 4 + 0]);
        float gg = tanhf(v.y + bias[jl * 4 + 1]);
        float fg = sigm(v.z + bias[jl * 4 + 2]);
        float og = sigm(v.w + bias[jl * 4 + 3]);
        float c = fg * cst[tid] + ig * gg;
        cst[tid] = c;
        unsigned x  = f2bf(og * tanhf(c));
        unsigned x1 = (unsigned)__shfl((int)x, lane + 1);
        unsigned x2 = (unsigned)__shfl((int)x, lane + 2);
        unsigned x3 = (unsigned)__shfl((int)x, lane + 3);
        if ((lane & 3) == 0) {
          ull val = (ull)(x | (x1 << 16)) | ((ull)(x2 | (x3 << 16)) << 32);
          unsigned short* dst = h0buf + (size_t)((p & 1) ^ 1) * BH + (size_t)b * HIDD + wg * 4;
          __hip_atomic_store((ull*)dst, val, __ATOMIC_RELAXED, __HIP_MEMORY_SCOPE_AGENT);
        }
      }
    } else {
      if (run1) {
        int t = tid - 256, b = t >> 2, jl = t & 3;
        const float* rr = red + 4096 + b * 16 + jl * 4;
        float4v v = *(const float4v*)rr;
        v += *(const float4v*)(rr + 1024);
        v += *(const float4v*)(rr + 2048);
        v += *(const float4v*)(rr + 3072);
        float ig = sigm(v.x + bias[16 + jl * 4 + 0]);
        float gg = tanhf(v.y + bias[16 + jl * 4 + 1]);
        float fg = sigm(v.z + bias[16 + jl * 4 + 2]);
        float og = sigm(v.w + bias[16 + jl * 4 + 3]);
        float c = fg * cst[tid] + ig * gg;
        cst[tid] = c;
        unsigned x  = f2bf(og * tanhf(c));
        unsigned x1 = (unsigned)__shfl((int)x, lane + 1);
        unsigned x2 = (unsigned)__shfl((int)x, lane + 2);
        unsigned x3 = (unsigned)__shfl((int)x, lane + 3);
        if ((lane & 3) == 0) {
          ull val = (ull)(x | (x1 << 16)) | ((ull)(x2 | (x3 << 16)) << 32);
          unsigned short* dst = h1buf + (size_t)(p & 1) * BH + (size_t)b * HIDD + wg * 4;
          __hip_atomic_store((ull*)dst, val, __ATOMIC_RELAXED, __HIP_MEMORY_SCOPE_AGENT);
        }
      }
    }
    if (p == SEQL) break;          // final h1(255) published (buf 0); done
    hbar(ctr, xcc, nloc, nxcd, ++tgt);
  }
}

// logits via MFMA: out[b][n] = sum_k h1[b][k] * Wout[k][n] + bout[n]
__global__ __launch_bounds__(256, 1)
void out_gemm_k(const char* __restrict__ ws, const float* __restrict__ Wout,
                const float* __restrict__ bout, float* __restrict__ out) {
  const unsigned short* h1 = (const unsigned short*)(ws + WS_H1G);  // bf16 [64][1024], buf 0
  const int tid = threadIdx.x, lane = tid & 63, wv = tid >> 6;
  const int l15 = lane & 15, quad = lane >> 4;
  const int n0 = blockIdx.x * 128 + wv * 32;
  float4v acc[4][2];
  #pragma unroll
  for (int m = 0; m < 4; ++m)
    #pragma unroll
    for (int f = 0; f < 2; ++f) acc[m][f] = (float4v){0.f, 0.f, 0.f, 0.f};

  for (int k0 = 0; k0 < HIDD; k0 += 32) {
    short8 a[4];
    #pragma unroll
    for (int m = 0; m < 4; ++m)
      a[m] = *(const short8*)(h1 + (size_t)(l15 + 16 * m) * HIDD + k0 + quad * 8);
    short8 bf[2];
    #pragma unroll
    for (int f = 0; f < 2; ++f) {
      int n = n0 + f * 16 + l15;
      #pragma unroll
      for (int j = 0; j < 8; ++j) {
        float w = Wout[(size_t)(k0 + quad * 8 + j) * NCLS + n];
        bf[f][j] = (short)f2bf(w);
      }
    }
    #pragma unroll
    for (int m = 0; m < 4; ++m)
      #pragma unroll
      for (int f = 0; f < 2; ++f)
        acc[m][f] = __builtin_amdgcn_mfma_f32_16x16x32_bf16(a[m], bf[f], acc[m][f], 0, 0, 0);
  }
  #pragma unroll
  for (int m = 0; m < 4; ++m)
    #pragma unroll
    for (int f = 0; f < 2; ++f) {
      int n = n0 + f * 16 + l15;
      float bb = bout[n];
      #pragma unroll
      for (int r = 0; r < 4; ++r) {
        int b = m * 16 + quad * 4 + r;
        out[(size_t)b * NCLS + n] = acc[m][f][r] + bb;
      }
    }
}

extern "C" void kernel_launch(void* const* d_in, const int* in_sizes, int n_in,
                              void* d_out, int out_size, void* d_ws, size_t ws_size,
                              hipStream_t stream) {
  const int*   X    = (const int*)d_in[0];
  const float* Cemb = (const float*)d_in[1];
  const float* Wi0  = (const float*)d_in[2];
  const float* bi0  = (const float*)d_in[3];
  const float* Wc0  = (const float*)d_in[4];
  const float* bc0  = (const float*)d_in[5];
  const float* Wf0  = (const float*)d_in[6];
  const float* bf0  = (const float*)d_in[7];
  const float* Wo0  = (const float*)d_in[8];
  const float* bo0  = (const float*)d_in[9];
  const float* Wi1  = (const float*)d_in[10];
  const float* bi1  = (const float*)d_in[11];
  const float* Wc1  = (const float*)d_in[12];
  const float* bc1  = (const float*)d_in[13];
  const float* Wf1  = (const float*)d_in[14];
  const float* bf1  = (const float*)d_in[15];
  const float* Wo1  = (const float*)d_in[16];
  const float* bo1  = (const float*)d_in[17];
  const float* Wout = (const float*)d_in[18];
  const float* bout = (const float*)d_in[19];
  float* out = (float*)d_out;
  char* ws = (char*)d_ws;

  hipFuncSetAttribute((const void*)lstm_k,
                      hipFuncAttributeMaxDynamicSharedMemorySize, SMEM_BYTES);

  init_bar_k<<<1, 512, 0, stream>>>(ws);
  embed_k<<<16384, 256, 0, stream>>>(X, Cemb, ws);
  lstm_k<<<NWG, 512, SMEM_BYTES, stream>>>(Wi0, Wc0, Wf0, Wo0, Wi1, Wc1, Wf1, Wo1,
                                           bi0, bc0, bf0, bo0, bi1, bc1, bf1, bo1, ws);
  out_gemm_k<<<250, 256, 0, stream>>>(ws, Wout, bout, out);
}

// Round 4
// 4398.970 us; speedup vs baseline: 1.0552x; 1.0085x over previous
//
#include <hip/hip_runtime.h>
#include <cstdint>
#include <cstddef>

#define NCLS 32000
#define EMBD 512
#define HIDD 1024
#define BATCH 64
#define SEQL 256
#define NWG 256
#define K0 1536
#define K1 2048
#define K0P (K0 + 8)
#define K1P (K1 + 8)
#define BH (BATCH * HIDD)          // 65536 elements
#define HBYTES (BH * 2)            // 131072 bytes per h buffer

typedef __attribute__((ext_vector_type(8))) short short8;
typedef __attribute__((ext_vector_type(4))) float float4v;
typedef unsigned long long ull;

// ---- workspace layout (bytes) ----
// ctr dwords: [0]=gctr, [16]=gen, [17]=dead (watchdog), [32+x]=cnt (membership),
//             [48]=sctr, [56]=sgen, [64+16x]=xctr, [192+16x]=xgen
#define WS_CTR   0                           // 2048 B reserved
#define WS_H0G   2048                        // 2 buffers bf16 [b][k]
#define WS_H1G   (WS_H0G + 2*HBYTES)
#define WS_XEMB  (WS_H1G + 2*HBYTES)         // 256*64*512*2 = 16 MB

#define SMEM_BYTES ((16*K0P + 16*K1P)*2 + (8192 + 32 + 512 + 8)*4)

__device__ __forceinline__ unsigned short f2bf(float f) {
  union { float f; uint32_t u; } x; x.f = f;
  uint32_t r = x.u + 0x7FFFu + ((x.u >> 16) & 1u);
  return (unsigned short)(r >> 16);
}

__device__ __forceinline__ float sigm(float x) {
  return 1.0f / (1.0f + __expf(-x));
}

// flat monotonic barrier (startup only) with deadlock watchdog
__device__ __forceinline__ void gbar(unsigned* bar, unsigned* gen, unsigned* dead,
                                     unsigned target) {
  __syncthreads();
  if (threadIdx.x == 0) {
    unsigned prev = __hip_atomic_fetch_add(bar, 1u, __ATOMIC_RELAXED, __HIP_MEMORY_SCOPE_AGENT);
    if (prev == target * NWG - 1u) {
      __hip_atomic_store(gen, target, __ATOMIC_RELAXED, __HIP_MEMORY_SCOPE_AGENT);
    } else {
      unsigned spin = 0;
      while (__hip_atomic_load(gen, __ATOMIC_RELAXED, __HIP_MEMORY_SCOPE_AGENT) < target) {
        if (__hip_atomic_load(dead, __ATOMIC_RELAXED, __HIP_MEMORY_SCOPE_AGENT) != 0u) break;
        if (++spin > 2000000u) {
          __hip_atomic_store(dead, 1u, __ATOMIC_RELAXED, __HIP_MEMORY_SCOPE_AGENT);
          break;
        }
        __builtin_amdgcn_s_sleep(1);
      }
    }
  }
  __syncthreads();
}

// hierarchical monotonic barrier: per-XCD aggregation. buffer_inv is issued by
// the XCD-last-arriver BEFORE the global release wait (overlaps the fan-in).
__device__ __forceinline__ void hbar(unsigned* ctr, unsigned xcc, unsigned nloc,
                                     unsigned nxcd, unsigned tgt) {
  __syncthreads();   // drains vmcnt -> this WG's publishes are visible
  if (threadIdx.x == 0) {
    unsigned* xctr = ctr + 64 + 16 * xcc;
    unsigned* xgen = ctr + 192 + 16 * xcc;
    unsigned* dead = ctr + 17;
    unsigned a = __hip_atomic_fetch_add(xctr, 1u, __ATOMIC_RELAXED, __HIP_MEMORY_SCOPE_AGENT);
    if (a == tgt * nloc - 1u) {            // last arriver on this XCD
      asm volatile("buffer_inv sc1\n\ts_waitcnt vmcnt(0)" ::: "memory");
      unsigned g = __hip_atomic_fetch_add(ctr, 1u, __ATOMIC_RELAXED, __HIP_MEMORY_SCOPE_AGENT);
      if (g == tgt * nxcd - 1u) {          // last arriver globally
        __hip_atomic_store(ctr + 16, tgt, __ATOMIC_RELAXED, __HIP_MEMORY_SCOPE_AGENT);
      } else {
        unsigned spin = 0;
        while (__hip_atomic_load(ctr + 16, __ATOMIC_RELAXED, __HIP_MEMORY_SCOPE_AGENT) < tgt) {
          if ((++spin & 63u) == 0u) {
            if (__hip_atomic_load(dead, __ATOMIC_RELAXED, __HIP_MEMORY_SCOPE_AGENT) != 0u) break;
            if (spin > 4000000u) {
              __hip_atomic_store(dead, 1u, __ATOMIC_RELAXED, __HIP_MEMORY_SCOPE_AGENT);
              break;
            }
          }
        }
      }
      __hip_atomic_store(xgen, tgt, __ATOMIC_RELAXED, __HIP_MEMORY_SCOPE_AGENT);
    } else {
      unsigned spin = 0;
      while (__hip_atomic_load(xgen, __ATOMIC_RELAXED, __HIP_MEMORY_SCOPE_AGENT) < tgt) {
        if ((++spin & 63u) == 0u) {
          if (__hip_atomic_load(dead, __ATOMIC_RELAXED, __HIP_MEMORY_SCOPE_AGENT) != 0u) break;
          if (spin > 4000000u) {
            __hip_atomic_store(dead, 1u, __ATOMIC_RELAXED, __HIP_MEMORY_SCOPE_AGENT);
            break;
          }
        }
      }
    }
  }
  __syncthreads();
}

__global__ void init_bar_k(char* ws) {
  if (threadIdx.x < 320) ((unsigned*)(ws + WS_CTR))[threadIdx.x] = 0u;
}

// gather embeddings -> bf16 xemb[t][b][e]
__global__ void embed_k(const int* __restrict__ X, const float* __restrict__ Cemb,
                        char* __restrict__ ws) {
  uint32_t p = blockIdx.x * 256u + threadIdx.x;   // pair index, 256*64*256 = 4194304
  uint32_t t = p >> 14;
  uint32_t r = p & 16383u;
  uint32_t b = r >> 8;
  uint32_t e2 = r & 255u;
  int row = X[b * SEQL + t];
  const float2 v = *(const float2*)(Cemb + (size_t)row * EMBD + (size_t)e2 * 2);
  uint32_t lo = f2bf(v.x), hi = f2bf(v.y);
  ((uint32_t*)(ws + WS_XEMB))[p] = (hi << 16) | lo;
}

__global__ __launch_bounds__(512, 1)
void lstm_k(const float* __restrict__ Wi0, const float* __restrict__ Wc0,
            const float* __restrict__ Wf0, const float* __restrict__ Wo0,
            const float* __restrict__ Wi1, const float* __restrict__ Wc1,
            const float* __restrict__ Wf1, const float* __restrict__ Wo1,
            const float* __restrict__ bi0, const float* __restrict__ bc0,
            const float* __restrict__ bf0, const float* __restrict__ bo0,
            const float* __restrict__ bi1, const float* __restrict__ bc1,
            const float* __restrict__ bf1, const float* __restrict__ bo1,
            char* ws) {
  const int wg   = blockIdx.x;
  const int tid  = threadIdx.x;
  const int lane = tid & 63;
  const int wv   = tid >> 6;        // 0..7
  const int l15  = lane & 15;
  const int quad = lane >> 4;

  extern __shared__ char smem[];
  unsigned short* w0 = (unsigned short*)smem;        // [16][K0P] bf16
  unsigned short* w1 = w0 + 16 * K0P;                // [16][K1P] bf16
  float* red  = (float*)(w1 + 16 * K1P);             // [8 waves][64 b][16 n]
  float* bias = red + 8192;                          // [32]
  float* cst  = bias + 32;                           // [512]
  int*   meta = (int*)(cst + 512);                   // [0]=nloc, [1]=nxcd

  unsigned short* h0buf = (unsigned short*)(ws + WS_H0G);
  unsigned short* h1buf = (unsigned short*)(ws + WS_H1G);
  const unsigned short* xemb = (const unsigned short*)(ws + WS_XEMB);
  unsigned* ctr = (unsigned*)(ws + WS_CTR);

  // XCD id (HW_REG_XCC_ID = hwreg 20, offset 0, width 4) [measured: learn_hip m09]
  const unsigned xcc = __builtin_amdgcn_s_getreg((3u << 11) | 20u) & 7u;

  // register XCD membership
  if (tid == 0)
    __hip_atomic_fetch_add(ctr + 32 + xcc, 1u, __ATOMIC_RELAXED, __HIP_MEMORY_SCOPE_AGENT);

  // ---- stage weights into LDS as bf16, layout [n = jl*4+g][k contiguous] ----
  {
    const float* W0g[4] = {Wi0, Wc0, Wf0, Wo0};
    const float* W1g[4] = {Wi1, Wc1, Wf1, Wo1};
    int jl = tid & 3;
    int kr = tid >> 2;            // 0..127
    int jg = wg * 4 + jl;
    for (int g = 0; g < 4; ++g) {
      unsigned short* dst0 = w0 + (jl * 4 + g) * K0P;
      const float* s0 = W0g[g] + jg;
      for (int k = kr; k < K0; k += 128) dst0[k] = f2bf(s0[(size_t)k * HIDD]);
      unsigned short* dst1 = w1 + (jl * 4 + g) * K1P;
      const float* s1 = W1g[g] + jg;
      for (int k = kr; k < K1; k += 128) dst1[k] = f2bf(s1[(size_t)k * HIDD]);
    }
  }
  if (tid < 32) {
    const float* B0g[4] = {bi0, bc0, bf0, bo0};
    const float* B1g[4] = {bi1, bc1, bf1, bo1};
    int lay = tid >> 4, idx = tid & 15, jl = idx >> 2, g = idx & 3;
    bias[tid] = (lay ? B1g[g] : B0g[g])[wg * 4 + jl];
  }
  cst[tid] = 0.f;
  if (tid < 128) {   // zero h state (buffer 0) via agent-coherent stores
    unsigned short* base = (tid < 64) ? h0buf : h1buf;
    int b = tid & 63;
    __hip_atomic_store((ull*)(base + (size_t)b * HIDD + wg * 4), 0ull,
                       __ATOMIC_RELAXED, __HIP_MEMORY_SCOPE_AGENT);
  }

  gbar(ctr + 48, ctr + 56, ctr + 17, 1u);   // startup: membership final, h zeroed, weights staged

  if (tid == 0) {
    int nl = (int)__hip_atomic_load(ctr + 32 + xcc, __ATOMIC_RELAXED, __HIP_MEMORY_SCOPE_AGENT);
    int nx = 0;
    for (int x = 0; x < 8; ++x)
      nx += (__hip_atomic_load(ctr + 32 + x, __ATOMIC_RELAXED, __HIP_MEMORY_SCOPE_AGENT) != 0u);
    meta[0] = nl; meta[1] = nx;
  }
  __syncthreads();
  const unsigned nloc = (unsigned)meta[0], nxcd = (unsigned)meta[1];

  unsigned tgt = 0;
  // phase p: waves 0-3 run L0(step p), waves 4-7 run L1(step p-1), concurrently.
  for (int p = 0; p <= SEQL; ++p) {
    const int run0 = (p < SEQL);
    const int run1 = (p >= 1);
    if (wv < 4) {
      if (run0) {
        const unsigned short* hp = h0buf + (size_t)(p & 1) * BH;        // h0(p-1)
        const unsigned short* xe = xemb + (size_t)p * BATCH * EMBD;
        float4v acc0 = {0.f,0.f,0.f,0.f}, acc1 = acc0, acc2 = acc0, acc3 = acc0;
        const int kbeg = wv * 384;
        // 2 batches x 6 iters; 24 loads in flight per batch -> 2 latency waits
        #pragma unroll
        for (int bb = 0; bb < 2; ++bb) {
          short8 d[6][4];
          #pragma unroll
          for (int i = 0; i < 6; ++i) {
            int k0 = kbeg + (bb * 6 + i) * 32;
            const unsigned short* ab; int st;
            if (k0 < HIDD) { ab = hp + k0 + quad * 8 + (size_t)l15 * HIDD; st = HIDD; }
            else           { ab = xe + (k0 - HIDD) + quad * 8 + (size_t)l15 * EMBD; st = EMBD; }
            d[i][0] = *(const short8*)(ab);
            d[i][1] = *(const short8*)(ab + 16 * st);
            d[i][2] = *(const short8*)(ab + 32 * st);
            d[i][3] = *(const short8*)(ab + 48 * st);
          }
          #pragma unroll
          for (int i = 0; i < 6; ++i) {
            int k0 = kbeg + (bb * 6 + i) * 32;
            short8 bfr = *(const short8*)(w0 + l15 * K0P + k0 + quad * 8);
            acc0 = __builtin_amdgcn_mfma_f32_16x16x32_bf16(d[i][0], bfr, acc0, 0, 0, 0);
            acc1 = __builtin_amdgcn_mfma_f32_16x16x32_bf16(d[i][1], bfr, acc1, 0, 0, 0);
            acc2 = __builtin_amdgcn_mfma_f32_16x16x32_bf16(d[i][2], bfr, acc2, 0, 0, 0);
            acc3 = __builtin_amdgcn_mfma_f32_16x16x32_bf16(d[i][3], bfr, acc3, 0, 0, 0);
          }
        }
        float* rw = red + wv * 1024 + quad * 64 + l15;
        #pragma unroll
        for (int r = 0; r < 4; ++r) {
          rw[r * 16]       = acc0[r];
          rw[256 + r * 16] = acc1[r];
          rw[512 + r * 16] = acc2[r];
          rw[768 + r * 16] = acc3[r];
        }
      }
    } else {
      if (run1) {
        const unsigned short* h1p = h1buf + (size_t)((p & 1) ^ 1) * BH;  // h1(p-2)
        const unsigned short* h0c = h0buf + (size_t)(p & 1) * BH;        // h0(p-1)
        float4v acc0 = {0.f,0.f,0.f,0.f}, acc1 = acc0, acc2 = acc0, acc3 = acc0;
        const int kbeg = (wv - 4) * 512;
        // 2 batches x 8 iters; 32 loads in flight per batch -> 2 latency waits
        #pragma unroll
        for (int bb = 0; bb < 2; ++bb) {
          short8 d[8][4];
          #pragma unroll
          for (int i = 0; i < 8; ++i) {
            int k0 = kbeg + (bb * 8 + i) * 32;
            const unsigned short* ab =
              ((k0 < HIDD) ? (h1p + k0) : (h0c + (k0 - HIDD))) + quad * 8 + (size_t)l15 * HIDD;
            d[i][0] = *(const short8*)(ab);
            d[i][1] = *(const short8*)(ab + 16 * HIDD);
            d[i][2] = *(const short8*)(ab + 32 * HIDD);
            d[i][3] = *(const short8*)(ab + 48 * HIDD);
          }
          #pragma unroll
          for (int i = 0; i < 8; ++i) {
            int k0 = kbeg + (bb * 8 + i) * 32;
            short8 bfr = *(const short8*)(w1 + l15 * K1P + k0 + quad * 8);
            acc0 = __builtin_amdgcn_mfma_f32_16x16x32_bf16(d[i][0], bfr, acc0, 0, 0, 0);
            acc1 = __builtin_amdgcn_mfma_f32_16x16x32_bf16(d[i][1], bfr, acc1, 0, 0, 0);
            acc2 = __builtin_amdgcn_mfma_f32_16x16x32_bf16(d[i][2], bfr, acc2, 0, 0, 0);
            acc3 = __builtin_amdgcn_mfma_f32_16x16x32_bf16(d[i][3], bfr, acc3, 0, 0, 0);
          }
        }
        float* rw = red + wv * 1024 + quad * 64 + l15;
        #pragma unroll
        for (int r = 0; r < 4; ++r) {
          rw[r * 16]       = acc0[r];
          rw[256 + r * 16] = acc1[r];
          rw[512 + r * 16] = acc2[r];
          rw[768 + r * 16] = acc3[r];
        }
      }
    }
    __syncthreads();
    // split epilogue: tid<256 -> L0 gates+publish, tid>=256 -> L1
    if (tid < 256) {
      if (run0) {
        int b = tid >> 2, jl = tid & 3;
        const float* rr = red + b * 16 + jl * 4;
        float4v v = *(const float4v*)rr;
        v += *(const float4v*)(rr + 1024);
        v += *(const float4v*)(rr + 2048);
        v += *(const float4v*)(rr + 3072);
        float ig = sigm(v.x + bias[jl * 4 + 0]);
        float gg = tanhf(v.y + bias[jl * 4 + 1]);
        float fg = sigm(v.z + bias[jl * 4 + 2]);
        float og = sigm(v.w + bias[jl * 4 + 3]);
        float c = fg * cst[tid] + ig * gg;
        cst[tid] = c;
        unsigned x  = f2bf(og * tanhf(c));
        unsigned x1 = (unsigned)__shfl((int)x, lane + 1);
        unsigned x2 = (unsigned)__shfl((int)x, lane + 2);
        unsigned x3 = (unsigned)__shfl((int)x, lane + 3);
        if ((lane & 3) == 0) {
          ull val = (ull)(x | (x1 << 16)) | ((ull)(x2 | (x3 << 16)) << 32);
          unsigned short* dst = h0buf + (size_t)((p & 1) ^ 1) * BH + (size_t)b * HIDD + wg * 4;
          __hip_atomic_store((ull*)dst, val, __ATOMIC_RELAXED, __HIP_MEMORY_SCOPE_AGENT);
        }
      }
    } else {
      if (run1) {
        int t = tid - 256, b = t >> 2, jl = t & 3;
        const float* rr = red + 4096 + b * 16 + jl * 4;
        float4v v = *(const float4v*)rr;
        v += *(const float4v*)(rr + 1024);
        v += *(const float4v*)(rr + 2048);
        v += *(const float4v*)(rr + 3072);
        float ig = sigm(v.x + bias[16 + jl * 4 + 0]);
        float gg = tanhf(v.y + bias[16 + jl * 4 + 1]);
        float fg = sigm(v.z + bias[16 + jl * 4 + 2]);
        float og = sigm(v.w + bias[16 + jl * 4 + 3]);
        float c = fg * cst[tid] + ig * gg;
        cst[tid] = c;
        unsigned x  = f2bf(og * tanhf(c));
        unsigned x1 = (unsigned)__shfl((int)x, lane + 1);
        unsigned x2 = (unsigned)__shfl((int)x, lane + 2);
        unsigned x3 = (unsigned)__shfl((int)x, lane + 3);
        if ((lane & 3) == 0) {
          ull val = (ull)(x | (x1 << 16)) | ((ull)(x2 | (x3 << 16)) << 32);
          unsigned short* dst = h1buf + (size_t)(p & 1) * BH + (size_t)b * HIDD + wg * 4;
          __hip_atomic_store((ull*)dst, val, __ATOMIC_RELAXED, __HIP_MEMORY_SCOPE_AGENT);
        }
      }
    }
    if (p == SEQL) break;          // final h1(255) published (buf 0); done
    hbar(ctr, xcc, nloc, nxcd, ++tgt);
  }
}

// logits via MFMA: out[b][n] = sum_k h1[b][k] * Wout[k][n] + bout[n]
__global__ __launch_bounds__(256, 1)
void out_gemm_k(const char* __restrict__ ws, const float* __restrict__ Wout,
                const float* __restrict__ bout, float* __restrict__ out) {
  const unsigned short* h1 = (const unsigned short*)(ws + WS_H1G);  // bf16 [64][1024], buf 0
  const int tid = threadIdx.x, lane = tid & 63, wv = tid >> 6;
  const int l15 = lane & 15, quad = lane >> 4;
  const int n0 = blockIdx.x * 128 + wv * 32;
  float4v acc[4][2];
  #pragma unroll
  for (int m = 0; m < 4; ++m)
    #pragma unroll
    for (int f = 0; f < 2; ++f) acc[m][f] = (float4v){0.f, 0.f, 0.f, 0.f};

  for (int k0 = 0; k0 < HIDD; k0 += 32) {
    short8 a[4];
    #pragma unroll
    for (int m = 0; m < 4; ++m)
      a[m] = *(const short8*)(h1 + (size_t)(l15 + 16 * m) * HIDD + k0 + quad * 8);
    short8 bf[2];
    #pragma unroll
    for (int f = 0; f < 2; ++f) {
      int n = n0 + f * 16 + l15;
      #pragma unroll
      for (int j = 0; j < 8; ++j) {
        float w = Wout[(size_t)(k0 + quad * 8 + j) * NCLS + n];
        bf[f][j] = (short)f2bf(w);
      }
    }
    #pragma unroll
    for (int m = 0; m < 4; ++m)
      #pragma unroll
      for (int f = 0; f < 2; ++f)
        acc[m][f] = __builtin_amdgcn_mfma_f32_16x16x32_bf16(a[m], bf[f], acc[m][f], 0, 0, 0);
  }
  #pragma unroll
  for (int m = 0; m < 4; ++m)
    #pragma unroll
    for (int f = 0; f < 2; ++f) {
      int n = n0 + f * 16 + l15;
      float bb = bout[n];
      #pragma unroll
      for (int r = 0; r < 4; ++r) {
        int b = m * 16 + quad * 4 + r;
        out[(size_t)b * NCLS + n] = acc[m][f][r] + bb;
      }
    }
}

extern "C" void kernel_launch(void* const* d_in, const int* in_sizes, int n_in,
                              void* d_out, int out_size, void* d_ws, size_t ws_size,
                              hipStream_t stream) {
  const int*   X    = (const int*)d_in[0];
  const float* Cemb = (const float*)d_in[1];
  const float* Wi0  = (const float*)d_in[2];
  const float* bi0  = (const float*)d_in[3];
  const float* Wc0  = (const float*)d_in[4];
  const float* bc0  = (const float*)d_in[5];
  const float* Wf0  = (const float*)d_in[6];
  const float* bf0  = (const float*)d_in[7];
  const float* Wo0  = (const float*)d_in[8];
  const float* bo0  = (const float*)d_in[9];
  const float* Wi1  = (const float*)d_in[10];
  const float* bi1  = (const float*)d_in[11];
  const float* Wc1  = (const float*)d_in[12];
  const float* bc1  = (const float*)d_in[13];
  const float* Wf1  = (const float*)d_in[14];
  const float* bf1  = (const float*)d_in[15];
  const float* Wo1  = (const float*)d_in[16];
  const float* bo1  = (const float*)d_in[17];
  const float* Wout = (const float*)d_in[18];
  const float* bout = (const float*)d_in[19];
  float* out = (float*)d_out;
  char* ws = (char*)d_ws;

  hipFuncSetAttribute((const void*)lstm_k,
                      hipFuncAttributeMaxDynamicSharedMemorySize, SMEM_BYTES);

  init_bar_k<<<1, 512, 0, stream>>>(ws);
  embed_k<<<16384, 256, 0, stream>>>(X, Cemb, ws);
  lstm_k<<<NWG, 512, SMEM_BYTES, stream>>>(Wi0, Wc0, Wf0, Wo0, Wi1, Wc1, Wf1, Wo1,
                                           bi0, bc0, bf0, bo0, bi1, bc1, bf1, bo1, ws);
  out_gemm_k<<<250, 256, 0, stream>>>(ws, Wout, bout, out);
}

// Round 5
// 4397.397 us; speedup vs baseline: 1.0556x; 1.0004x over previous
//
#include <hip/hip_runtime.h>
#include <cstdint>
#include <cstddef>

#define NCLS 32000
#define EMBD 512
#define HIDD 1024
#define BATCH 64
#define SEQL 256
#define NWG 256
#define K0 1536
#define K1 2048
#define K0P (K0 + 8)
#define K1P (K1 + 8)
#define BH (BATCH * HIDD)          // 65536 elements
#define HBYTES (BH * 2)            // 131072 bytes per h buffer

typedef __attribute__((ext_vector_type(8))) short short8;
typedef __attribute__((ext_vector_type(4))) float float4v;
typedef __attribute__((ext_vector_type(4))) int int4v;
typedef unsigned long long ull;

// ---- workspace layout (bytes) ----
// ctr dwords: [0]=gctr, [16]=gen, [17]=dead (watchdog), [32+x]=cnt (membership),
//             [48]=sctr, [56]=sgen, [64+16x]=xctr, [192+16x]=xgen
#define WS_CTR   0                           // 2048 B reserved
#define WS_H0G   2048                        // 2 buffers bf16 [b][k]
#define WS_H1G   (WS_H0G + 2*HBYTES)
#define WS_XEMB  (WS_H1G + 2*HBYTES)         // 256*64*512*2 = 16 MB

#define SMEM_BYTES ((16*K0P + 16*K1P)*2 + (8192 + 32 + 512 + 8)*4)

__device__ __forceinline__ unsigned short f2bf(float f) {
  union { float f; uint32_t u; } x; x.f = f;
  uint32_t r = x.u + 0x7FFFu + ((x.u >> 16) & 1u);
  return (unsigned short)(r >> 16);
}

__device__ __forceinline__ float sigm(float x) {
  return 1.0f / (1.0f + __expf(-x));
}

// coherent (agent-scope, L1+L2 read-through) 16B load — same semantics class
// as __hip_atomic_load(AGENT) which the barrier polls already rely on.
__device__ __forceinline__ short8 cload(const unsigned short* p) {
  int4v r;
  asm volatile("global_load_dwordx4 %0, %1, off sc0 sc1"
               : "=&v"(r) : "v"(p) : "memory");
  union { int4v i; short8 s; } u; u.i = r; return u.s;
}

// flat monotonic barrier (startup only) with deadlock watchdog
__device__ __forceinline__ void gbar(unsigned* bar, unsigned* gen, unsigned* dead,
                                     unsigned target) {
  __syncthreads();
  if (threadIdx.x == 0) {
    unsigned prev = __hip_atomic_fetch_add(bar, 1u, __ATOMIC_RELAXED, __HIP_MEMORY_SCOPE_AGENT);
    if (prev == target * NWG - 1u) {
      __hip_atomic_store(gen, target, __ATOMIC_RELAXED, __HIP_MEMORY_SCOPE_AGENT);
    } else {
      unsigned spin = 0;
      while (__hip_atomic_load(gen, __ATOMIC_RELAXED, __HIP_MEMORY_SCOPE_AGENT) < target) {
        if (__hip_atomic_load(dead, __ATOMIC_RELAXED, __HIP_MEMORY_SCOPE_AGENT) != 0u) break;
        if (++spin > 2000000u) {
          __hip_atomic_store(dead, 1u, __ATOMIC_RELAXED, __HIP_MEMORY_SCOPE_AGENT);
          break;
        }
        __builtin_amdgcn_s_sleep(1);
      }
    }
  }
  __syncthreads();
}

// hierarchical monotonic barrier: per-XCD aggregation, pure counters.
// NO buffer_inv: h-state reads are coherent (sc0 sc1) L2-bypass loads, so no
// stale L2 lines can be observed and no cache maintenance is on the critical path.
__device__ __forceinline__ void hbar(unsigned* ctr, unsigned xcc, unsigned nloc,
                                     unsigned nxcd, unsigned tgt) {
  __syncthreads();   // drains vmcnt -> this WG's sc1 publishes are acked
  if (threadIdx.x == 0) {
    unsigned* xctr = ctr + 64 + 16 * xcc;
    unsigned* xgen = ctr + 192 + 16 * xcc;
    unsigned* dead = ctr + 17;
    unsigned a = __hip_atomic_fetch_add(xctr, 1u, __ATOMIC_RELAXED, __HIP_MEMORY_SCOPE_AGENT);
    if (a == tgt * nloc - 1u) {            // last arriver on this XCD
      unsigned g = __hip_atomic_fetch_add(ctr, 1u, __ATOMIC_RELAXED, __HIP_MEMORY_SCOPE_AGENT);
      if (g == tgt * nxcd - 1u) {          // last arriver globally
        __hip_atomic_store(ctr + 16, tgt, __ATOMIC_RELAXED, __HIP_MEMORY_SCOPE_AGENT);
      } else {
        unsigned spin = 0;
        while (__hip_atomic_load(ctr + 16, __ATOMIC_RELAXED, __HIP_MEMORY_SCOPE_AGENT) < tgt) {
          if ((++spin & 63u) == 0u) {
            if (__hip_atomic_load(dead, __ATOMIC_RELAXED, __HIP_MEMORY_SCOPE_AGENT) != 0u) break;
            if (spin > 4000000u) {
              __hip_atomic_store(dead, 1u, __ATOMIC_RELAXED, __HIP_MEMORY_SCOPE_AGENT);
              break;
            }
          }
        }
      }
      __hip_atomic_store(xgen, tgt, __ATOMIC_RELAXED, __HIP_MEMORY_SCOPE_AGENT);
    } else {
      unsigned spin = 0;
      while (__hip_atomic_load(xgen, __ATOMIC_RELAXED, __HIP_MEMORY_SCOPE_AGENT) < tgt) {
        if ((++spin & 63u) == 0u) {
          if (__hip_atomic_load(dead, __ATOMIC_RELAXED, __HIP_MEMORY_SCOPE_AGENT) != 0u) break;
          if (spin > 4000000u) {
            __hip_atomic_store(dead, 1u, __ATOMIC_RELAXED, __HIP_MEMORY_SCOPE_AGENT);
            break;
          }
        }
      }
    }
  }
  __syncthreads();
}

__global__ void init_bar_k(char* ws) {
  if (threadIdx.x < 320) ((unsigned*)(ws + WS_CTR))[threadIdx.x] = 0u;
}

// gather embeddings -> bf16 xemb[t][b][e]
__global__ void embed_k(const int* __restrict__ X, const float* __restrict__ Cemb,
                        char* __restrict__ ws) {
  uint32_t p = blockIdx.x * 256u + threadIdx.x;   // pair index, 256*64*256 = 4194304
  uint32_t t = p >> 14;
  uint32_t r = p & 16383u;
  uint32_t b = r >> 8;
  uint32_t e2 = r & 255u;
  int row = X[b * SEQL + t];
  const float2 v = *(const float2*)(Cemb + (size_t)row * EMBD + (size_t)e2 * 2);
  uint32_t lo = f2bf(v.x), hi = f2bf(v.y);
  ((uint32_t*)(ws + WS_XEMB))[p] = (hi << 16) | lo;
}

__global__ __launch_bounds__(512, 1)
void lstm_k(const float* __restrict__ Wi0, const float* __restrict__ Wc0,
            const float* __restrict__ Wf0, const float* __restrict__ Wo0,
            const float* __restrict__ Wi1, const float* __restrict__ Wc1,
            const float* __restrict__ Wf1, const float* __restrict__ Wo1,
            const float* __restrict__ bi0, const float* __restrict__ bc0,
            const float* __restrict__ bf0, const float* __restrict__ bo0,
            const float* __restrict__ bi1, const float* __restrict__ bc1,
            const float* __restrict__ bf1, const float* __restrict__ bo1,
            char* ws) {
  const int wg   = blockIdx.x;
  const int tid  = threadIdx.x;
  const int lane = tid & 63;
  const int wv   = tid >> 6;        // 0..7
  const int l15  = lane & 15;
  const int quad = lane >> 4;

  extern __shared__ char smem[];
  unsigned short* w0 = (unsigned short*)smem;        // [16][K0P] bf16
  unsigned short* w1 = w0 + 16 * K0P;                // [16][K1P] bf16
  float* red  = (float*)(w1 + 16 * K1P);             // [8 waves][64 b][16 n]
  float* bias = red + 8192;                          // [32]
  float* cst  = bias + 32;                           // [512]
  int*   meta = (int*)(cst + 512);                   // [0]=nloc, [1]=nxcd

  unsigned short* h0buf = (unsigned short*)(ws + WS_H0G);
  unsigned short* h1buf = (unsigned short*)(ws + WS_H1G);
  const unsigned short* xemb = (const unsigned short*)(ws + WS_XEMB);
  unsigned* ctr = (unsigned*)(ws + WS_CTR);

  // XCD id (HW_REG_XCC_ID = hwreg 20, offset 0, width 4) [measured: learn_hip m09]
  const unsigned xcc = __builtin_amdgcn_s_getreg((3u << 11) | 20u) & 7u;

  // register XCD membership
  if (tid == 0)
    __hip_atomic_fetch_add(ctr + 32 + xcc, 1u, __ATOMIC_RELAXED, __HIP_MEMORY_SCOPE_AGENT);

  // ---- stage weights into LDS as bf16, layout [n = jl*4+g][k contiguous] ----
  {
    const float* W0g[4] = {Wi0, Wc0, Wf0, Wo0};
    const float* W1g[4] = {Wi1, Wc1, Wf1, Wo1};
    int jl = tid & 3;
    int kr = tid >> 2;            // 0..127
    int jg = wg * 4 + jl;
    for (int g = 0; g < 4; ++g) {
      unsigned short* dst0 = w0 + (jl * 4 + g) * K0P;
      const float* s0 = W0g[g] + jg;
      for (int k = kr; k < K0; k += 128) dst0[k] = f2bf(s0[(size_t)k * HIDD]);
      unsigned short* dst1 = w1 + (jl * 4 + g) * K1P;
      const float* s1 = W1g[g] + jg;
      for (int k = kr; k < K1; k += 128) dst1[k] = f2bf(s1[(size_t)k * HIDD]);
    }
  }
  if (tid < 32) {
    const float* B0g[4] = {bi0, bc0, bf0, bo0};
    const float* B1g[4] = {bi1, bc1, bf1, bo1};
    int lay = tid >> 4, idx = tid & 15, jl = idx >> 2, g = idx & 3;
    bias[tid] = (lay ? B1g[g] : B0g[g])[wg * 4 + jl];
  }
  cst[tid] = 0.f;
  if (tid < 128) {   // zero h state (buffer 0) via agent-coherent stores
    unsigned short* base = (tid < 64) ? h0buf : h1buf;
    int b = tid & 63;
    __hip_atomic_store((ull*)(base + (size_t)b * HIDD + wg * 4), 0ull,
                       __ATOMIC_RELAXED, __HIP_MEMORY_SCOPE_AGENT);
  }

  gbar(ctr + 48, ctr + 56, ctr + 17, 1u);   // startup: membership final, h zeroed, weights staged

  if (tid == 0) {
    int nl = (int)__hip_atomic_load(ctr + 32 + xcc, __ATOMIC_RELAXED, __HIP_MEMORY_SCOPE_AGENT);
    int nx = 0;
    for (int x = 0; x < 8; ++x)
      nx += (__hip_atomic_load(ctr + 32 + x, __ATOMIC_RELAXED, __HIP_MEMORY_SCOPE_AGENT) != 0u);
    meta[0] = nl; meta[1] = nx;
  }
  __syncthreads();
  const unsigned nloc = (unsigned)meta[0], nxcd = (unsigned)meta[1];

  unsigned tgt = 0;
  // phase p: waves 0-3 run L0(step p), waves 4-7 run L1(step p-1), concurrently.
  for (int p = 0; p <= SEQL; ++p) {
    const int run0 = (p < SEQL);
    const int run1 = (p >= 1);
    if (wv < 4) {
      if (run0) {
        const unsigned short* hp = h0buf + (size_t)(p & 1) * BH;        // h0(p-1)
        const unsigned short* xe = xemb + (size_t)p * BATCH * EMBD;
        float4v acc0 = {0.f,0.f,0.f,0.f}, acc1 = acc0, acc2 = acc0, acc3 = acc0;
        const int kbeg = wv * 384;
        // 2 batches x 6 iters; 24 coherent loads issued back-to-back, ONE wait.
        #pragma unroll
        for (int bb = 0; bb < 2; ++bb) {
          short8 d[6][4];
          #pragma unroll
          for (int i = 0; i < 6; ++i) {
            int k0 = kbeg + (bb * 6 + i) * 32;
            if (k0 < HIDD) {   // h0(p-1): cross-XCD -> coherent loads
              const unsigned short* ab = hp + k0 + quad * 8 + (size_t)l15 * HIDD;
              d[i][0] = cload(ab);
              d[i][1] = cload(ab + 16 * HIDD);
              d[i][2] = cload(ab + 32 * HIDD);
              d[i][3] = cload(ab + 48 * HIDD);
            } else {           // xemb: immutable -> normal cached loads
              const unsigned short* ab = xe + (k0 - HIDD) + quad * 8 + (size_t)l15 * EMBD;
              d[i][0] = *(const short8*)(ab);
              d[i][1] = *(const short8*)(ab + 16 * EMBD);
              d[i][2] = *(const short8*)(ab + 32 * EMBD);
              d[i][3] = *(const short8*)(ab + 48 * EMBD);
            }
          }
          asm volatile("s_waitcnt vmcnt(0)" ::: "memory");
          __builtin_amdgcn_sched_barrier(0);   // rule #18: no MFMA hoisting above the wait
          #pragma unroll
          for (int i = 0; i < 6; ++i) {
            int k0 = kbeg + (bb * 6 + i) * 32;
            short8 bfr = *(const short8*)(w0 + l15 * K0P + k0 + quad * 8);
            acc0 = __builtin_amdgcn_mfma_f32_16x16x32_bf16(d[i][0], bfr, acc0, 0, 0, 0);
            acc1 = __builtin_amdgcn_mfma_f32_16x16x32_bf16(d[i][1], bfr, acc1, 0, 0, 0);
            acc2 = __builtin_amdgcn_mfma_f32_16x16x32_bf16(d[i][2], bfr, acc2, 0, 0, 0);
            acc3 = __builtin_amdgcn_mfma_f32_16x16x32_bf16(d[i][3], bfr, acc3, 0, 0, 0);
          }
        }
        float* rw = red + wv * 1024 + quad * 64 + l15;
        #pragma unroll
        for (int r = 0; r < 4; ++r) {
          rw[r * 16]       = acc0[r];
          rw[256 + r * 16] = acc1[r];
          rw[512 + r * 16] = acc2[r];
          rw[768 + r * 16] = acc3[r];
        }
      }
    } else {
      if (run1) {
        const unsigned short* h1p = h1buf + (size_t)((p & 1) ^ 1) * BH;  // h1(p-2)
        const unsigned short* h0c = h0buf + (size_t)(p & 1) * BH;        // h0(p-1)
        float4v acc0 = {0.f,0.f,0.f,0.f}, acc1 = acc0, acc2 = acc0, acc3 = acc0;
        const int kbeg = (wv - 4) * 512;
        // 2 batches x 8 iters; 32 coherent loads in flight, ONE wait per batch.
        #pragma unroll
        for (int bb = 0; bb < 2; ++bb) {
          short8 d[8][4];
          #pragma unroll
          for (int i = 0; i < 8; ++i) {
            int k0 = kbeg + (bb * 8 + i) * 32;
            const unsigned short* ab =
              ((k0 < HIDD) ? (h1p + k0) : (h0c + (k0 - HIDD))) + quad * 8 + (size_t)l15 * HIDD;
            d[i][0] = cload(ab);
            d[i][1] = cload(ab + 16 * HIDD);
            d[i][2] = cload(ab + 32 * HIDD);
            d[i][3] = cload(ab + 48 * HIDD);
          }
          asm volatile("s_waitcnt vmcnt(0)" ::: "memory");
          __builtin_amdgcn_sched_barrier(0);
          #pragma unroll
          for (int i = 0; i < 8; ++i) {
            int k0 = kbeg + (bb * 8 + i) * 32;
            short8 bfr = *(const short8*)(w1 + l15 * K1P + k0 + quad * 8);
            acc0 = __builtin_amdgcn_mfma_f32_16x16x32_bf16(d[i][0], bfr, acc0, 0, 0, 0);
            acc1 = __builtin_amdgcn_mfma_f32_16x16x32_bf16(d[i][1], bfr, acc1, 0, 0, 0);
            acc2 = __builtin_amdgcn_mfma_f32_16x16x32_bf16(d[i][2], bfr, acc2, 0, 0, 0);
            acc3 = __builtin_amdgcn_mfma_f32_16x16x32_bf16(d[i][3], bfr, acc3, 0, 0, 0);
          }
        }
        float* rw = red + wv * 1024 + quad * 64 + l15;
        #pragma unroll
        for (int r = 0; r < 4; ++r) {
          rw[r * 16]       = acc0[r];
          rw[256 + r * 16] = acc1[r];
          rw[512 + r * 16] = acc2[r];
          rw[768 + r * 16] = acc3[r];
        }
      }
    }
    __syncthreads();
    // split epilogue: tid<256 -> L0 gates+publish, tid>=256 -> L1
    if (tid < 256) {
      if (run0) {
        int b = tid >> 2, jl = tid & 3;
        const float* rr = red + b * 16 + jl * 4;
        float4v v = *(const float4v*)rr;
        v += *(const float4v*)(rr + 1024);
        v += *(const float4v*)(rr + 2048);
        v += *(const float4v*)(rr + 3072);
        float ig = sigm(v.x + bias[jl * 4 + 0]);
        float gg = tanhf(v.y + bias[jl * 4 + 1]);
        float fg = sigm(v.z + bias[jl * 4 + 2]);
        float og = sigm(v.w + bias[jl * 4 + 3]);
        float c = fg * cst[tid] + ig * gg;
        cst[tid] = c;
        unsigned x  = f2bf(og * tanhf(c));
        unsigned x1 = (unsigned)__shfl((int)x, lane + 1);
        unsigned x2 = (unsigned)__shfl((int)x, lane + 2);
        unsigned x3 = (unsigned)__shfl((int)x, lane + 3);
        if ((lane & 3) == 0) {
          ull val = (ull)(x | (x1 << 16)) | ((ull)(x2 | (x3 << 16)) << 32);
          unsigned short* dst = h0buf + (size_t)((p & 1) ^ 1) * BH + (size_t)b * HIDD + wg * 4;
          __hip_atomic_store((ull*)dst, val, __ATOMIC_RELAXED, __HIP_MEMORY_SCOPE_AGENT);
        }
      }
    } else {
      if (run1) {
        int t = tid - 256, b = t >> 2, jl = t & 3;
        const float* rr = red + 4096 + b * 16 + jl * 4;
        float4v v = *(const float4v*)rr;
        v += *(const float4v*)(rr + 1024);
        v += *(const float4v*)(rr + 2048);
        v += *(const float4v*)(rr + 3072);
        float ig = sigm(v.x + bias[16 + jl * 4 + 0]);
        float gg = tanhf(v.y + bias[16 + jl * 4 + 1]);
        float fg = sigm(v.z + bias[16 + jl * 4 + 2]);
        float og = sigm(v.w + bias[16 + jl * 4 + 3]);
        float c = fg * cst[tid] + ig * gg;
        cst[tid] = c;
        unsigned x  = f2bf(og * tanhf(c));
        unsigned x1 = (unsigned)__shfl((int)x, lane + 1);
        unsigned x2 = (unsigned)__shfl((int)x, lane + 2);
        unsigned x3 = (unsigned)__shfl((int)x, lane + 3);
        if ((lane & 3) == 0) {
          ull val = (ull)(x | (x1 << 16)) | ((ull)(x2 | (x3 << 16)) << 32);
          unsigned short* dst = h1buf + (size_t)(p & 1) * BH + (size_t)b * HIDD + wg * 4;
          __hip_atomic_store((ull*)dst, val, __ATOMIC_RELAXED, __HIP_MEMORY_SCOPE_AGENT);
        }
      }
    }
    if (p == SEQL) break;          // final h1(255) published (buf 0); done
    hbar(ctr, xcc, nloc, nxcd, ++tgt);
  }
}

// logits via MFMA: out[b][n] = sum_k h1[b][k] * Wout[k][n] + bout[n]
__global__ __launch_bounds__(256, 1)
void out_gemm_k(const char* __restrict__ ws, const float* __restrict__ Wout,
                const float* __restrict__ bout, float* __restrict__ out) {
  const unsigned short* h1 = (const unsigned short*)(ws + WS_H1G);  // bf16 [64][1024], buf 0
  const int tid = threadIdx.x, lane = tid & 63, wv = tid >> 6;
  const int l15 = lane & 15, quad = lane >> 4;
  const int n0 = blockIdx.x * 128 + wv * 32;
  float4v acc[4][2];
  #pragma unroll
  for (int m = 0; m < 4; ++m)
    #pragma unroll
    for (int f = 0; f < 2; ++f) acc[m][f] = (float4v){0.f, 0.f, 0.f, 0.f};

  for (int k0 = 0; k0 < HIDD; k0 += 32) {
    short8 a[4];
    #pragma unroll
    for (int m = 0; m < 4; ++m)
      a[m] = *(const short8*)(h1 + (size_t)(l15 + 16 * m) * HIDD + k0 + quad * 8);
    short8 bf[2];
    #pragma unroll
    for (int f = 0; f < 2; ++f) {
      int n = n0 + f * 16 + l15;
      #pragma unroll
      for (int j = 0; j < 8; ++j) {
        float w = Wout[(size_t)(k0 + quad * 8 + j) * NCLS + n];
        bf[f][j] = (short)f2bf(w);
      }
    }
    #pragma unroll
    for (int m = 0; m < 4; ++m)
      #pragma unroll
      for (int f = 0; f < 2; ++f)
        acc[m][f] = __builtin_amdgcn_mfma_f32_16x16x32_bf16(a[m], bf[f], acc[m][f], 0, 0, 0);
  }
  #pragma unroll
  for (int m = 0; m < 4; ++m)
    #pragma unroll
    for (int f = 0; f < 2; ++f) {
      int n = n0 + f * 16 + l15;
      float bb = bout[n];
      #pragma unroll
      for (int r = 0; r < 4; ++r) {
        int b = m * 16 + quad * 4 + r;
        out[(size_t)b * NCLS + n] = acc[m][f][r] + bb;
      }
    }
}

extern "C" void kernel_launch(void* const* d_in, const int* in_sizes, int n_in,
                              void* d_out, int out_size, void* d_ws, size_t ws_size,
                              hipStream_t stream) {
  const int*   X    = (const int*)d_in[0];
  const float* Cemb = (const float*)d_in[1];
  const float* Wi0  = (const float*)d_in[2];
  const float* bi0  = (const float*)d_in[3];
  const float* Wc0  = (const float*)d_in[4];
  const float* bc0  = (const float*)d_in[5];
  const float* Wf0  = (const float*)d_in[6];
  const float* bf0  = (const float*)d_in[7];
  const float* Wo0  = (const float*)d_in[8];
  const float* bo0  = (const float*)d_in[9];
  const float* Wi1  = (const float*)d_in[10];
  const float* bi1  = (const float*)d_in[11];
  const float* Wc1  = (const float*)d_in[12];
  const float* bc1  = (const float*)d_in[13];
  const float* Wf1  = (const float*)d_in[14];
  const float* bf1  = (const float*)d_in[15];
  const float* Wo1  = (const float*)d_in[16];
  const float* bo1  = (const float*)d_in[17];
  const float* Wout = (const float*)d_in[18];
  const float* bout = (const float*)d_in[19];
  float* out = (float*)d_out;
  char* ws = (char*)d_ws;

  hipFuncSetAttribute((const void*)lstm_k,
                      hipFuncAttributeMaxDynamicSharedMemorySize, SMEM_BYTES);

  init_bar_k<<<1, 512, 0, stream>>>(ws);
  embed_k<<<16384, 256, 0, stream>>>(X, Cemb, ws);
  lstm_k<<<NWG, 512, SMEM_BYTES, stream>>>(Wi0, Wc0, Wf0, Wo0, Wi1, Wc1, Wf1, Wo1,
                                           bi0, bc0, bf0, bo0, bi1, bc1, bf1, bo1, ws);
  out_gemm_k<<<250, 256, 0, stream>>>(ws, Wout, bout, out);
}

// Round 6
// 2903.114 us; speedup vs baseline: 1.5989x; 1.5147x over previous
//
#include <hip/hip_runtime.h>
#include <cstdint>
#include <cstddef>

#define NCLS 32000
#define EMBD 512
#define HIDD 1024
#define BATCH 64
#define SEQL 256
#define NWG 256
#define K0 1536
#define K1 2048
#define K0P (K0 + 2)
#define K1P (K1 + 2)
#define BH (BATCH * HIDD)          // 65536 elements
#define HBYTES (BH * 2)            // 131072 bytes per h buffer

// ---- tiled layout: buf[k/32][64 b][32 k] bf16 (4KB tiles, k-contiguous rows of 64B)
// element (b,k) -> (k>>5)*2048 + b*32 + (k&31)

typedef __attribute__((ext_vector_type(8))) short short8;
typedef __attribute__((ext_vector_type(4))) float float4v;
typedef unsigned long long ull;

// ---- workspace layout (bytes) ----
#define WS_CTR   0                           // 2048 B reserved
#define WS_H0G   2048                        // 2 buffers bf16 tiled
#define WS_H1G   (WS_H0G + 2*HBYTES)
#define WS_XEMB  (WS_H1G + 2*HBYTES)         // 256*64*512*2 = 16 MB, tiled per t

#define SMEM_BYTES ((16*K0P + 16*K1P)*2 + (8192 + 32 + 512 + 8)*4)

__device__ __forceinline__ unsigned short f2bf(float f) {
  union { float f; uint32_t u; } x; x.f = f;
  uint32_t r = x.u + 0x7FFFu + ((x.u >> 16) & 1u);
  return (unsigned short)(r >> 16);
}

__device__ __forceinline__ float sigm(float x) {
  return 1.0f / (1.0f + __expf(-x));
}

// flat monotonic barrier (startup only) with deadlock watchdog
__device__ __forceinline__ void gbar(unsigned* bar, unsigned* gen, unsigned* dead,
                                     unsigned target) {
  __syncthreads();
  if (threadIdx.x == 0) {
    unsigned prev = __hip_atomic_fetch_add(bar, 1u, __ATOMIC_RELAXED, __HIP_MEMORY_SCOPE_AGENT);
    if (prev == target * NWG - 1u) {
      __hip_atomic_store(gen, target, __ATOMIC_RELAXED, __HIP_MEMORY_SCOPE_AGENT);
    } else {
      unsigned spin = 0;
      while (__hip_atomic_load(gen, __ATOMIC_RELAXED, __HIP_MEMORY_SCOPE_AGENT) < target) {
        if (__hip_atomic_load(dead, __ATOMIC_RELAXED, __HIP_MEMORY_SCOPE_AGENT) != 0u) break;
        if (++spin > 2000000u) {
          __hip_atomic_store(dead, 1u, __ATOMIC_RELAXED, __HIP_MEMORY_SCOPE_AGENT);
          break;
        }
        __builtin_amdgcn_s_sleep(1);
      }
    }
  }
  __syncthreads();
}

// hierarchical monotonic barrier: per-XCD aggregation; buffer_inv issued by the
// XCD-last-arriver BEFORE the global release wait (overlaps the fan-in).
__device__ __forceinline__ void hbar(unsigned* ctr, unsigned xcc, unsigned nloc,
                                     unsigned nxcd, unsigned tgt) {
  __syncthreads();   // drains vmcnt -> this WG's publishes are acked
  if (threadIdx.x == 0) {
    unsigned* xctr = ctr + 64 + 16 * xcc;
    unsigned* xgen = ctr + 192 + 16 * xcc;
    unsigned* dead = ctr + 17;
    unsigned a = __hip_atomic_fetch_add(xctr, 1u, __ATOMIC_RELAXED, __HIP_MEMORY_SCOPE_AGENT);
    if (a == tgt * nloc - 1u) {            // last arriver on this XCD
      asm volatile("buffer_inv sc1\n\ts_waitcnt vmcnt(0)" ::: "memory");
      unsigned g = __hip_atomic_fetch_add(ctr, 1u, __ATOMIC_RELAXED, __HIP_MEMORY_SCOPE_AGENT);
      if (g == tgt * nxcd - 1u) {          // last arriver globally
        __hip_atomic_store(ctr + 16, tgt, __ATOMIC_RELAXED, __HIP_MEMORY_SCOPE_AGENT);
      } else {
        unsigned spin = 0;
        while (__hip_atomic_load(ctr + 16, __ATOMIC_RELAXED, __HIP_MEMORY_SCOPE_AGENT) < tgt) {
          if ((++spin & 63u) == 0u) {
            if (__hip_atomic_load(dead, __ATOMIC_RELAXED, __HIP_MEMORY_SCOPE_AGENT) != 0u) break;
            if (spin > 4000000u) {
              __hip_atomic_store(dead, 1u, __ATOMIC_RELAXED, __HIP_MEMORY_SCOPE_AGENT);
              break;
            }
          }
        }
      }
      __hip_atomic_store(xgen, tgt, __ATOMIC_RELAXED, __HIP_MEMORY_SCOPE_AGENT);
    } else {
      unsigned spin = 0;
      while (__hip_atomic_load(xgen, __ATOMIC_RELAXED, __HIP_MEMORY_SCOPE_AGENT) < tgt) {
        if ((++spin & 63u) == 0u) {
          if (__hip_atomic_load(dead, __ATOMIC_RELAXED, __HIP_MEMORY_SCOPE_AGENT) != 0u) break;
          if (spin > 4000000u) {
            __hip_atomic_store(dead, 1u, __ATOMIC_RELAXED, __HIP_MEMORY_SCOPE_AGENT);
            break;
          }
        }
      }
    }
  }
  __syncthreads();
}

__global__ void init_bar_k(char* ws) {
  if (threadIdx.x < 320) ((unsigned*)(ws + WS_CTR))[threadIdx.x] = 0u;
}

// gather embeddings -> bf16 xemb, tiled [t][e/32][64 b][32 e]
__global__ void embed_k(const int* __restrict__ X, const float* __restrict__ Cemb,
                        char* __restrict__ ws) {
  uint32_t p = blockIdx.x * 256u + threadIdx.x;   // pair index, 256*64*256 = 4194304
  uint32_t t = p >> 14;
  uint32_t r = p & 16383u;
  uint32_t b = r >> 8;
  uint32_t e2 = r & 255u;                         // pair index within row (e = 2*e2)
  int row = X[b * SEQL + t];
  const float2 v = *(const float2*)(Cemb + (size_t)row * EMBD + (size_t)e2 * 2);
  uint32_t lo = f2bf(v.x), hi = f2bf(v.y);
  // tiled dword index: t*16384 + (e2>>4)*1024 + b*16 + (e2&15)
  uint32_t dw = t * 16384u + (e2 >> 4) * 1024u + b * 16u + (e2 & 15u);
  ((uint32_t*)(ws + WS_XEMB))[dw] = (hi << 16) | lo;
}

__global__ __launch_bounds__(512, 1)
void lstm_k(const float* __restrict__ Wi0, const float* __restrict__ Wc0,
            const float* __restrict__ Wf0, const float* __restrict__ Wo0,
            const float* __restrict__ Wi1, const float* __restrict__ Wc1,
            const float* __restrict__ Wf1, const float* __restrict__ Wo1,
            const float* __restrict__ bi0, const float* __restrict__ bc0,
            const float* __restrict__ bf0, const float* __restrict__ bo0,
            const float* __restrict__ bi1, const float* __restrict__ bc1,
            const float* __restrict__ bf1, const float* __restrict__ bo1,
            char* ws) {
  const int wg   = blockIdx.x;
  const int tid  = threadIdx.x;
  const int lane = tid & 63;
  const int wv   = tid >> 6;        // 0..7
  const int l15  = lane & 15;
  const int quad = lane >> 4;

  extern __shared__ char smem[];
  unsigned short* w0 = (unsigned short*)smem;        // [16][K0P] bf16
  unsigned short* w1 = w0 + 16 * K0P;                // [16][K1P] bf16
  float* red  = (float*)(w1 + 16 * K1P);             // [8 waves][64 b][16 n]
  float* bias = red + 8192;                          // [32]
  float* cst  = bias + 32;                           // [512]
  int*   meta = (int*)(cst + 512);                   // [0]=nloc, [1]=nxcd

  unsigned short* h0buf = (unsigned short*)(ws + WS_H0G);
  unsigned short* h1buf = (unsigned short*)(ws + WS_H1G);
  const unsigned short* xemb = (const unsigned short*)(ws + WS_XEMB);
  unsigned* ctr = (unsigned*)(ws + WS_CTR);

  // XCD id (HW_REG_XCC_ID = hwreg 20, offset 0, width 4) [measured: learn_hip m09]
  const unsigned xcc = __builtin_amdgcn_s_getreg((3u << 11) | 20u) & 7u;

  // register XCD membership
  if (tid == 0)
    __hip_atomic_fetch_add(ctr + 32 + xcc, 1u, __ATOMIC_RELAXED, __HIP_MEMORY_SCOPE_AGENT);

  // ---- stage weights into LDS as bf16, layout [n = jl*4+g][k contiguous] ----
  {
    const float* W0g[4] = {Wi0, Wc0, Wf0, Wo0};
    const float* W1g[4] = {Wi1, Wc1, Wf1, Wo1};
    int jl = tid & 3;
    int kr = tid >> 2;            // 0..127
    int jg = wg * 4 + jl;
    for (int g = 0; g < 4; ++g) {
      unsigned short* dst0 = w0 + (jl * 4 + g) * K0P;
      const float* s0 = W0g[g] + jg;
      for (int k = kr; k < K0; k += 128) dst0[k] = f2bf(s0[(size_t)k * HIDD]);
      unsigned short* dst1 = w1 + (jl * 4 + g) * K1P;
      const float* s1 = W1g[g] + jg;
      for (int k = kr; k < K1; k += 128) dst1[k] = f2bf(s1[(size_t)k * HIDD]);
    }
  }
  if (tid < 32) {
    const float* B0g[4] = {bi0, bc0, bf0, bo0};
    const float* B1g[4] = {bi1, bc1, bf1, bo1};
    int lay = tid >> 4, idx = tid & 15, jl = idx >> 2, g = idx & 3;
    bias[tid] = (lay ? B1g[g] : B0g[g])[wg * 4 + jl];
  }
  cst[tid] = 0.f;
  if (tid < 128) {   // zero h state (buffer 0), tiled addressing
    unsigned short* base = (tid < 64) ? h0buf : h1buf;
    int b = tid & 63;
    __hip_atomic_store((ull*)(base + ((wg >> 3) << 11) + b * 32 + (wg & 7) * 4), 0ull,
                       __ATOMIC_RELAXED, __HIP_MEMORY_SCOPE_AGENT);
  }

  gbar(ctr + 48, ctr + 56, ctr + 17, 1u);   // startup: membership final, h zeroed, weights staged

  if (tid == 0) {
    int nl = (int)__hip_atomic_load(ctr + 32 + xcc, __ATOMIC_RELAXED, __HIP_MEMORY_SCOPE_AGENT);
    int nx = 0;
    for (int x = 0; x < 8; ++x)
      nx += (__hip_atomic_load(ctr + 32 + x, __ATOMIC_RELAXED, __HIP_MEMORY_SCOPE_AGENT) != 0u);
    meta[0] = nl; meta[1] = nx;
  }
  __syncthreads();
  const unsigned nloc = (unsigned)meta[0], nxcd = (unsigned)meta[1];

  const int lofs = l15 * 32 + quad * 8;   // per-lane offset within a 2048-elem tile group

  unsigned tgt = 0;
  // phase p: waves 0-3 run L0(step p), waves 4-7 run L1(step p-1), concurrently.
  for (int p = 0; p <= SEQL; ++p) {
    const int run0 = (p < SEQL);
    const int run1 = (p >= 1);
    if (wv < 4) {
      if (run0) {
        const unsigned short* hp = h0buf + (size_t)(p & 1) * BH;        // h0(p-1) tiled
        const unsigned short* xe = xemb + (size_t)p * BATCH * EMBD;     // x(p) tiled
        float4v acc0 = {0.f,0.f,0.f,0.f}, acc1 = acc0, acc2 = acc0, acc3 = acc0;
        const int kbeg = wv * 384;
        #pragma unroll
        for (int bb = 0; bb < 2; ++bb) {
          short8 d[6][4];
          #pragma unroll
          for (int i = 0; i < 6; ++i) {
            int k0 = kbeg + (bb * 6 + i) * 32;
            const unsigned short* base =
              (k0 < HIDD) ? (hp + ((k0 >> 5) << 11)) : (xe + (((k0 - HIDD) >> 5) << 11));
            const unsigned short* ab = base + lofs;       // 1KB-contiguous per wave-load
            d[i][0] = *(const short8*)(ab);
            d[i][1] = *(const short8*)(ab + 512);
            d[i][2] = *(const short8*)(ab + 1024);
            d[i][3] = *(const short8*)(ab + 1536);
          }
          #pragma unroll
          for (int i = 0; i < 6; ++i) {
            int k0 = kbeg + (bb * 6 + i) * 32;
            short8 bfr = *(const short8*)(w0 + l15 * K0P + k0 + quad * 8);
            acc0 = __builtin_amdgcn_mfma_f32_16x16x32_bf16(d[i][0], bfr, acc0, 0, 0, 0);
            acc1 = __builtin_amdgcn_mfma_f32_16x16x32_bf16(d[i][1], bfr, acc1, 0, 0, 0);
            acc2 = __builtin_amdgcn_mfma_f32_16x16x32_bf16(d[i][2], bfr, acc2, 0, 0, 0);
            acc3 = __builtin_amdgcn_mfma_f32_16x16x32_bf16(d[i][3], bfr, acc3, 0, 0, 0);
          }
        }
        float* rw = red + wv * 1024 + quad * 64 + l15;
        #pragma unroll
        for (int r = 0; r < 4; ++r) {
          rw[r * 16]       = acc0[r];
          rw[256 + r * 16] = acc1[r];
          rw[512 + r * 16] = acc2[r];
          rw[768 + r * 16] = acc3[r];
        }
      }
    } else {
      if (run1) {
        const unsigned short* h1p = h1buf + (size_t)((p & 1) ^ 1) * BH;  // h1(p-2) tiled
        const unsigned short* h0c = h0buf + (size_t)(p & 1) * BH;        // h0(p-1) tiled
        float4v acc0 = {0.f,0.f,0.f,0.f}, acc1 = acc0, acc2 = acc0, acc3 = acc0;
        const int kbeg = (wv - 4) * 512;
        #pragma unroll
        for (int bb = 0; bb < 2; ++bb) {
          short8 d[8][4];
          #pragma unroll
          for (int i = 0; i < 8; ++i) {
            int k0 = kbeg + (bb * 8 + i) * 32;
            const unsigned short* base =
              (k0 < HIDD) ? (h1p + ((k0 >> 5) << 11)) : (h0c + (((k0 - HIDD) >> 5) << 11));
            const unsigned short* ab = base + lofs;
            d[i][0] = *(const short8*)(ab);
            d[i][1] = *(const short8*)(ab + 512);
            d[i][2] = *(const short8*)(ab + 1024);
            d[i][3] = *(const short8*)(ab + 1536);
          }
          #pragma unroll
          for (int i = 0; i < 8; ++i) {
            int k0 = kbeg + (bb * 8 + i) * 32;
            short8 bfr = *(const short8*)(w1 + l15 * K1P + k0 + quad * 8);
            acc0 = __builtin_amdgcn_mfma_f32_16x16x32_bf16(d[i][0], bfr, acc0, 0, 0, 0);
            acc1 = __builtin_amdgcn_mfma_f32_16x16x32_bf16(d[i][1], bfr, acc1, 0, 0, 0);
            acc2 = __builtin_amdgcn_mfma_f32_16x16x32_bf16(d[i][2], bfr, acc2, 0, 0, 0);
            acc3 = __builtin_amdgcn_mfma_f32_16x16x32_bf16(d[i][3], bfr, acc3, 0, 0, 0);
          }
        }
        float* rw = red + wv * 1024 + quad * 64 + l15;
        #pragma unroll
        for (int r = 0; r < 4; ++r) {
          rw[r * 16]       = acc0[r];
          rw[256 + r * 16] = acc1[r];
          rw[512 + r * 16] = acc2[r];
          rw[768 + r * 16] = acc3[r];
        }
      }
    }
    __syncthreads();
    // split epilogue: tid<256 -> L0 gates+publish, tid>=256 -> L1
    if (tid < 256) {
      if (run0) {
        int b = tid >> 2, jl = tid & 3;
        const float* rr = red + b * 16 + jl * 4;
        float4v v = *(const float4v*)rr;
        v += *(const float4v*)(rr + 1024);
        v += *(const float4v*)(rr + 2048);
        v += *(const float4v*)(rr + 3072);
        float ig = sigm(v.x + bias[jl * 4 + 0]);
        float gg = tanhf(v.y + bias[jl * 4 + 1]);
        float fg = sigm(v.z + bias[jl * 4 + 2]);
        float og = sigm(v.w + bias[jl * 4 + 3]);
        float c = fg * cst[tid] + ig * gg;
        cst[tid] = c;
        unsigned x  = f2bf(og * tanhf(c));
        unsigned x1 = (unsigned)__shfl((int)x, lane + 1);
        unsigned x2 = (unsigned)__shfl((int)x, lane + 2);
        unsigned x3 = (unsigned)__shfl((int)x, lane + 3);
        if ((lane & 3) == 0) {
          ull val = (ull)(x | (x1 << 16)) | ((ull)(x2 | (x3 << 16)) << 32);
          unsigned short* dst = h0buf + (size_t)((p & 1) ^ 1) * BH
                              + ((wg >> 3) << 11) + b * 32 + (wg & 7) * 4;
          __hip_atomic_store((ull*)dst, val, __ATOMIC_RELAXED, __HIP_MEMORY_SCOPE_AGENT);
        }
      }
    } else {
      if (run1) {
        int t = tid - 256, b = t >> 2, jl = t & 3;
        const float* rr = red + 4096 + b * 16 + jl * 4;
        float4v v = *(const float4v*)rr;
        v += *(const float4v*)(rr + 1024);
        v += *(const float4v*)(rr + 2048);
        v += *(const float4v*)(rr + 3072);
        float ig = sigm(v.x + bias[16 + jl * 4 + 0]);
        float gg = tanhf(v.y + bias[16 + jl * 4 + 1]);
        float fg = sigm(v.z + bias[16 + jl * 4 + 2]);
        float og = sigm(v.w + bias[16 + jl * 4 + 3]);
        float c = fg * cst[tid] + ig * gg;
        cst[tid] = c;
        unsigned x  = f2bf(og * tanhf(c));
        unsigned x1 = (unsigned)__shfl((int)x, lane + 1);
        unsigned x2 = (unsigned)__shfl((int)x, lane + 2);
        unsigned x3 = (unsigned)__shfl((int)x, lane + 3);
        if ((lane & 3) == 0) {
          ull val = (ull)(x | (x1 << 16)) | ((ull)(x2 | (x3 << 16)) << 32);
          unsigned short* dst = h1buf + (size_t)(p & 1) * BH
                              + ((wg >> 3) << 11) + b * 32 + (wg & 7) * 4;
          __hip_atomic_store((ull*)dst, val, __ATOMIC_RELAXED, __HIP_MEMORY_SCOPE_AGENT);
        }
      }
    }
    if (p == SEQL) break;          // final h1(255) published (buf 0); done
    hbar(ctr, xcc, nloc, nxcd, ++tgt);
  }
}

// logits via MFMA: out[b][n] = sum_k h1[b][k] * Wout[k][n] + bout[n]
__global__ __launch_bounds__(256, 1)
void out_gemm_k(const char* __restrict__ ws, const float* __restrict__ Wout,
                const float* __restrict__ bout, float* __restrict__ out) {
  const unsigned short* h1 = (const unsigned short*)(ws + WS_H1G);  // bf16 tiled, buf 0
  const int tid = threadIdx.x, lane = tid & 63, wv = tid >> 6;
  const int l15 = lane & 15, quad = lane >> 4;
  const int n0 = blockIdx.x * 128 + wv * 32;
  float4v acc[4][2];
  #pragma unroll
  for (int m = 0; m < 4; ++m)
    #pragma unroll
    for (int f = 0; f < 2; ++f) acc[m][f] = (float4v){0.f, 0.f, 0.f, 0.f};

  for (int k0 = 0; k0 < HIDD; k0 += 32) {
    const unsigned short* tb = h1 + ((k0 >> 5) << 11) + l15 * 32 + quad * 8;
    short8 a[4];
    #pragma unroll
    for (int m = 0; m < 4; ++m)
      a[m] = *(const short8*)(tb + m * 512);
    short8 bf[2];
    #pragma unroll
    for (int f = 0; f < 2; ++f) {
      int n = n0 + f * 16 + l15;
      #pragma unroll
      for (int j = 0; j < 8; ++j) {
        float w = Wout[(size_t)(k0 + quad * 8 + j) * NCLS + n];
        bf[f][j] = (short)f2bf(w);
      }
    }
    #pragma unroll
    for (int m = 0; m < 4; ++m)
      #pragma unroll
      for (int f = 0; f < 2; ++f)
        acc[m][f] = __builtin_amdgcn_mfma_f32_16x16x32_bf16(a[m], bf[f], acc[m][f], 0, 0, 0);
  }
  #pragma unroll
  for (int m = 0; m < 4; ++m)
    #pragma unroll
    for (int f = 0; f < 2; ++f) {
      int n = n0 + f * 16 + l15;
      float bb = bout[n];
      #pragma unroll
      for (int r = 0; r < 4; ++r) {
        int b = m * 16 + quad * 4 + r;
        out[(size_t)b * NCLS + n] = acc[m][f][r] + bb;
      }
    }
}

extern "C" void kernel_launch(void* const* d_in, const int* in_sizes, int n_in,
                              void* d_out, int out_size, void* d_ws, size_t ws_size,
                              hipStream_t stream) {
  const int*   X    = (const int*)d_in[0];
  const float* Cemb = (const float*)d_in[1];
  const float* Wi0  = (const float*)d_in[2];
  const float* bi0  = (const float*)d_in[3];
  const float* Wc0  = (const float*)d_in[4];
  const float* bc0  = (const float*)d_in[5];
  const float* Wf0  = (const float*)d_in[6];
  const float* bf0  = (const float*)d_in[7];
  const float* Wo0  = (const float*)d_in[8];
  const float* bo0  = (const float*)d_in[9];
  const float* Wi1  = (const float*)d_in[10];
  const float* bi1  = (const float*)d_in[11];
  const float* Wc1  = (const float*)d_in[12];
  const float* bc1  = (const float*)d_in[13];
  const float* Wf1  = (const float*)d_in[14];
  const float* bf1  = (const float*)d_in[15];
  const float* Wo1  = (const float*)d_in[16];
  const float* bo1  = (const float*)d_in[17];
  const float* Wout = (const float*)d_in[18];
  const float* bout = (const float*)d_in[19];
  float* out = (float*)d_out;
  char* ws = (char*)d_ws;

  hipFuncSetAttribute((const void*)lstm_k,
                      hipFuncAttributeMaxDynamicSharedMemorySize, SMEM_BYTES);

  init_bar_k<<<1, 512, 0, stream>>>(ws);
  embed_k<<<16384, 256, 0, stream>>>(X, Cemb, ws);
  lstm_k<<<NWG, 512, SMEM_BYTES, stream>>>(Wi0, Wc0, Wf0, Wo0, Wi1, Wc1, Wf1, Wo1,
                                           bi0, bc0, bf0, bo0, bi1, bc1, bf1, bo1, ws);
  out_gemm_k<<<250, 256, 0, stream>>>(ws, Wout, bout, out);
}

// Round 8
// 2828.903 us; speedup vs baseline: 1.6408x; 1.0262x over previous
//
#include <hip/hip_runtime.h>
#include <cstdint>
#include <cstddef>

#define NCLS 32000
#define EMBD 512
#define HIDD 1024
#define BATCH 64
#define SEQL 256
#define NWG 256
#define BH (BATCH * HIDD)          // 65536 elements
#define HBYTES (BH * 2)            // 131072 bytes per h buffer

// ---- tiled layout: buf[k/32][64 b][32 k] bf16 (4KB tiles, k-contiguous rows of 64B)
// element (b,k) -> (k>>5)*2048 + b*32 + (k&31)

typedef __attribute__((ext_vector_type(8))) short short8;
typedef __attribute__((ext_vector_type(4))) float float4v;
typedef unsigned long long ull;
typedef unsigned short ushort;

// ---- workspace layout (bytes) ----
#define WS_CTR   0                           // 2048 B reserved
#define WS_H0G   2048                        // 2 buffers bf16 tiled
#define WS_H1G   (WS_H0G + 2*HBYTES)
#define WS_XEMB  (WS_H1G + 2*HBYTES)         // 16 MB, tiled per t

// ---- LDS: h0stage [31 blocks][2048 ushort] = 126976 B | red [8][64][16] f32 = 32768 B | meta 16 B
#define LDS_RED_OFF  126976
#define LDS_META_OFF (126976 + 32768)
#define SMEM_BYTES   (126976 + 32768 + 16)

__device__ __forceinline__ ushort f2bf(float f) {
  union { float f; uint32_t u; } x; x.f = f;
  uint32_t r = x.u + 0x7FFFu + ((x.u >> 16) & 1u);
  return (ushort)(r >> 16);
}

__device__ __forceinline__ float sigm(float x) {
  return 1.0f / (1.0f + __expf(-x));
}

// flat monotonic barrier (startup only) with deadlock watchdog
__device__ __forceinline__ void gbar(unsigned* bar, unsigned* gen, unsigned* dead,
                                     unsigned target) {
  __syncthreads();
  if (threadIdx.x == 0) {
    unsigned prev = __hip_atomic_fetch_add(bar, 1u, __ATOMIC_RELAXED, __HIP_MEMORY_SCOPE_AGENT);
    if (prev == target * NWG - 1u) {
      __hip_atomic_store(gen, target, __ATOMIC_RELAXED, __HIP_MEMORY_SCOPE_AGENT);
    } else {
      unsigned spin = 0;
      while (__hip_atomic_load(gen, __ATOMIC_RELAXED, __HIP_MEMORY_SCOPE_AGENT) < target) {
        if (__hip_atomic_load(dead, __ATOMIC_RELAXED, __HIP_MEMORY_SCOPE_AGENT) != 0u) break;
        if (++spin > 2000000u) {
          __hip_atomic_store(dead, 1u, __ATOMIC_RELAXED, __HIP_MEMORY_SCOPE_AGENT);
          break;
        }
        __builtin_amdgcn_s_sleep(1);
      }
    }
  }
  __syncthreads();
}

// hierarchical monotonic barrier: per-XCD aggregation; buffer_inv issued by the
// XCD-last-arriver BEFORE the global release wait (overlaps the fan-in).
__device__ __forceinline__ void hbar(unsigned* ctr, unsigned xcc, unsigned nloc,
                                     unsigned nxcd, unsigned tgt) {
  __syncthreads();   // drains vmcnt -> this WG's publishes are acked
  if (threadIdx.x == 0) {
    unsigned* xctr = ctr + 64 + 16 * xcc;
    unsigned* xgen = ctr + 192 + 16 * xcc;
    unsigned* dead = ctr + 17;
    unsigned a = __hip_atomic_fetch_add(xctr, 1u, __ATOMIC_RELAXED, __HIP_MEMORY_SCOPE_AGENT);
    if (a == tgt * nloc - 1u) {            // last arriver on this XCD
      asm volatile("buffer_inv sc1\n\ts_waitcnt vmcnt(0)" ::: "memory");
      unsigned g = __hip_atomic_fetch_add(ctr, 1u, __ATOMIC_RELAXED, __HIP_MEMORY_SCOPE_AGENT);
      if (g == tgt * nxcd - 1u) {          // last arriver globally
        __hip_atomic_store(ctr + 16, tgt, __ATOMIC_RELAXED, __HIP_MEMORY_SCOPE_AGENT);
      } else {
        unsigned spin = 0;
        while (__hip_atomic_load(ctr + 16, __ATOMIC_RELAXED, __HIP_MEMORY_SCOPE_AGENT) < tgt) {
          if ((++spin & 63u) == 0u) {
            if (__hip_atomic_load(dead, __ATOMIC_RELAXED, __HIP_MEMORY_SCOPE_AGENT) != 0u) break;
            if (spin > 4000000u) {
              __hip_atomic_store(dead, 1u, __ATOMIC_RELAXED, __HIP_MEMORY_SCOPE_AGENT);
              break;
            }
          }
        }
      }
      __hip_atomic_store(xgen, tgt, __ATOMIC_RELAXED, __HIP_MEMORY_SCOPE_AGENT);
    } else {
      unsigned spin = 0;
      while (__hip_atomic_load(xgen, __ATOMIC_RELAXED, __HIP_MEMORY_SCOPE_AGENT) < tgt) {
        if ((++spin & 63u) == 0u) {
          if (__hip_atomic_load(dead, __ATOMIC_RELAXED, __HIP_MEMORY_SCOPE_AGENT) != 0u) break;
          if (spin > 4000000u) {
            __hip_atomic_store(dead, 1u, __ATOMIC_RELAXED, __HIP_MEMORY_SCOPE_AGENT);
            break;
          }
        }
      }
    }
  }
  __syncthreads();
}

__global__ void init_bar_k(char* ws) {
  if (threadIdx.x < 320) ((unsigned*)(ws + WS_CTR))[threadIdx.x] = 0u;
}

// gather embeddings -> bf16 xemb, tiled [t][e/32][64 b][32 e]
__global__ void embed_k(const int* __restrict__ X, const float* __restrict__ Cemb,
                        char* __restrict__ ws) {
  uint32_t p = blockIdx.x * 256u + threadIdx.x;   // pair index, 256*64*256 = 4194304
  uint32_t t = p >> 14;
  uint32_t r = p & 16383u;
  uint32_t b = r >> 8;
  uint32_t e2 = r & 255u;                         // pair index within row (e = 2*e2)
  int row = X[b * SEQL + t];
  const float2 v = *(const float2*)(Cemb + (size_t)row * EMBD + (size_t)e2 * 2);
  uint32_t lo = f2bf(v.x), hi = f2bf(v.y);
  uint32_t dw = t * 16384u + (e2 >> 4) * 1024u + b * 16u + (e2 & 15u);
  ((uint32_t*)(ws + WS_XEMB))[dw] = (hi << 16) | lo;
}

__global__ __launch_bounds__(512, 1)
void lstm_k(const float* __restrict__ Wi0, const float* __restrict__ Wc0,
            const float* __restrict__ Wf0, const float* __restrict__ Wo0,
            const float* __restrict__ Wi1, const float* __restrict__ Wc1,
            const float* __restrict__ Wf1, const float* __restrict__ Wo1,
            const float* __restrict__ bi0, const float* __restrict__ bc0,
            const float* __restrict__ bf0, const float* __restrict__ bo0,
            const float* __restrict__ bi1, const float* __restrict__ bc1,
            const float* __restrict__ bf1, const float* __restrict__ bo1,
            char* ws) {
  const int wg   = blockIdx.x;
  const int tid  = threadIdx.x;
  const int lane = tid & 63;
  const int wv   = tid >> 6;        // 0..7
  const int l15  = lane & 15;
  const int quad = lane >> 4;

  extern __shared__ char smem[];
  ushort* h0st = (ushort*)smem;                       // [31][2048] fragment-layout h0 stage
  float*  red  = (float*)(smem + LDS_RED_OFF);        // [8 waves][64 b][16 n]
  int*    meta = (int*)(smem + LDS_META_OFF);         // [0]=nloc, [1]=nxcd

  ushort* h0buf = (ushort*)(ws + WS_H0G);
  ushort* h1buf = (ushort*)(ws + WS_H1G);
  const ushort* xemb = (const ushort*)(ws + WS_XEMB);
  unsigned* ctr = (unsigned*)(ws + WS_CTR);

  // XCD id (HW_REG_XCC_ID = hwreg 20, offset 0, width 4) [measured: learn_hip m09]
  const unsigned xcc = __builtin_amdgcn_s_getreg((3u << 11) | 20u) & 7u;

  if (tid == 0)
    __hip_atomic_fetch_add(ctr + 32 + xcc, 1u, __ATOMIC_RELAXED, __HIP_MEMORY_SCOPE_AGENT);

  // ---- weight fragments -> VGPRs via LDS bounce (one-time) ----
  // B-fragment for n-rows [16] (= 4 units x 4 gates), per-wave private K-slices.
  short8 bfr[16];
  {
    ushort* scr = (ushort*)smem;     // scratch overlaps h0stage (pre-loop only)
    // stage w0 rows [16][1536]
    {
      const float* W0g[4] = {Wi0, Wc0, Wf0, Wo0};
      int jl = tid & 3, kr = tid >> 2, jg = wg * 4 + jl;
      for (int g = 0; g < 4; ++g) {
        ushort* dst = scr + (jl * 4 + g) * 1536;
        const float* s = W0g[g] + jg;
        for (int k = kr; k < 1536; k += 128) dst[k] = f2bf(s[(size_t)k * HIDD]);
      }
    }
    __syncthreads();
    if (wv < 4) {
      #pragma unroll
      for (int j = 0; j < 12; ++j)
        bfr[j] = *(const short8*)(scr + l15 * 1536 + (12 * wv + j) * 32 + quad * 8);
    }
    __syncthreads();
    // stage w1 rows [16][2048]
    {
      const float* W1g[4] = {Wi1, Wc1, Wf1, Wo1};
      int jl = tid & 3, kr = tid >> 2, jg = wg * 4 + jl;
      for (int g = 0; g < 4; ++g) {
        ushort* dst = scr + (jl * 4 + g) * 2048;
        const float* s = W1g[g] + jg;
        for (int k = kr; k < 2048; k += 128) dst[k] = f2bf(s[(size_t)k * HIDD]);
      }
    }
    __syncthreads();
    if (wv >= 4) {
      #pragma unroll
      for (int j = 0; j < 8; ++j)   // h1p slice
        bfr[j] = *(const short8*)(scr + l15 * 2048 + ((wv - 4) * 256 + j * 32) + quad * 8);
      #pragma unroll
      for (int j = 0; j < 8; ++j)   // h0c slice
        bfr[8 + j] = *(const short8*)(scr + l15 * 2048 + 1024 + ((wv - 4) * 256 + j * 32) + quad * 8);
    }
    __syncthreads();
  }

  // ---- per-epilogue-thread bias + c-state in registers ----
  float bs0 = 0.f, bs1 = 0.f, bs2 = 0.f, bs3 = 0.f, cstr = 0.f;
  {
    int jl = tid & 3, jg = wg * 4 + jl;
    if (tid < 256) { bs0 = bi0[jg]; bs1 = bc0[jg]; bs2 = bf0[jg]; bs3 = bo0[jg]; }
    else           { bs0 = bi1[jg]; bs1 = bc1[jg]; bs2 = bf1[jg]; bs3 = bo1[jg]; }
  }

  if (tid < 128) {   // zero h state (buffer 0), tiled addressing
    ushort* base = (tid < 64) ? h0buf : h1buf;
    int b = tid & 63;
    __hip_atomic_store((ull*)(base + ((wg >> 3) << 11) + b * 32 + (wg & 7) * 4), 0ull,
                       __ATOMIC_RELAXED, __HIP_MEMORY_SCOPE_AGENT);
  }

  gbar(ctr + 48, ctr + 56, ctr + 17, 1u);   // startup: membership final, h zeroed, weights ready

  if (tid == 0) {
    int nl = (int)__hip_atomic_load(ctr + 32 + xcc, __ATOMIC_RELAXED, __HIP_MEMORY_SCOPE_AGENT);
    int nx = 0;
    for (int x = 0; x < 8; ++x)
      nx += (__hip_atomic_load(ctr + 32 + x, __ATOMIC_RELAXED, __HIP_MEMORY_SCOPE_AGENT) != 0u);
    meta[0] = nl; meta[1] = nx;
  }
  __syncthreads();
  const unsigned nloc = (unsigned)meta[0], nxcd = (unsigned)meta[1];

  const int lofs = l15 * 32 + quad * 8;   // per-lane offset within a 2048-elem tile

  unsigned tgt = 0;
  // phase p: part1 {L0 full (+h0 LDS staging) | L1 h1p half} -> syncA ->
  //          {L0 epilogue || L1 h0c half from LDS} -> syncB -> L1 epilogue -> hbar
  for (int p = 0; p <= SEQL; ++p) {
    const int run0 = (p < SEQL);
    const int run1 = (p >= 1);
    float4v acc0 = {0.f,0.f,0.f,0.f}, acc1 = acc0, acc2 = acc0, acc3 = acc0;

    // ================= part 1 =================
    if (wv < 4) {
      if (run0) {
        const ushort* hp = h0buf + (size_t)(p & 1) * BH;        // h0(p-1) tiled
        const ushort* xe = xemb + (size_t)p * BATCH * EMBD;     // x(p) tiled
        #pragma unroll
        for (int bb = 0; bb < 2; ++bb) {
          short8 d[6][4];
          #pragma unroll
          for (int i = 0; i < 6; ++i) {
            int kb = 12 * wv + bb * 6 + i;
            const ushort* base = (kb < 32) ? (hp + kb * 2048) : (xe + (kb - 32) * 2048);
            const ushort* ab = base + lofs;
            d[i][0] = *(const short8*)(ab);
            d[i][1] = *(const short8*)(ab + 512);
            d[i][2] = *(const short8*)(ab + 1024);
            d[i][3] = *(const short8*)(ab + 1536);
          }
          #pragma unroll
          for (int i = 0; i < 6; ++i) {
            int kb = 12 * wv + bb * 6 + i;
            if (kb <= 30) {           // stage h0 fragment for L1's h0c pass
              ushort* sp = h0st + kb * 2048 + lofs;
              *(short8*)(sp)        = d[i][0];
              *(short8*)(sp + 512)  = d[i][1];
              *(short8*)(sp + 1024) = d[i][2];
              *(short8*)(sp + 1536) = d[i][3];
            }
            short8 w = bfr[bb * 6 + i];
            acc0 = __builtin_amdgcn_mfma_f32_16x16x32_bf16(d[i][0], w, acc0, 0, 0, 0);
            acc1 = __builtin_amdgcn_mfma_f32_16x16x32_bf16(d[i][1], w, acc1, 0, 0, 0);
            acc2 = __builtin_amdgcn_mfma_f32_16x16x32_bf16(d[i][2], w, acc2, 0, 0, 0);
            acc3 = __builtin_amdgcn_mfma_f32_16x16x32_bf16(d[i][3], w, acc3, 0, 0, 0);
          }
        }
        float* rw = red + wv * 1024 + quad * 64 + l15;
        #pragma unroll
        for (int r = 0; r < 4; ++r) {
          rw[r * 16]       = acc0[r];
          rw[256 + r * 16] = acc1[r];
          rw[512 + r * 16] = acc2[r];
          rw[768 + r * 16] = acc3[r];
        }
      }
    } else {
      if (run1) {   // h1p half (8 blocks, global)
        const ushort* h1p = h1buf + (size_t)((p & 1) ^ 1) * BH;  // h1(p-2) tiled
        #pragma unroll
        for (int bb = 0; bb < 2; ++bb) {
          short8 d[4][4];
          #pragma unroll
          for (int i = 0; i < 4; ++i) {
            int kb = (wv - 4) * 8 + bb * 4 + i;
            const ushort* ab = h1p + kb * 2048 + lofs;
            d[i][0] = *(const short8*)(ab);
            d[i][1] = *(const short8*)(ab + 512);
            d[i][2] = *(const short8*)(ab + 1024);
            d[i][3] = *(const short8*)(ab + 1536);
          }
          #pragma unroll
          for (int i = 0; i < 4; ++i) {
            short8 w = bfr[bb * 4 + i];
            acc0 = __builtin_amdgcn_mfma_f32_16x16x32_bf16(d[i][0], w, acc0, 0, 0, 0);
            acc1 = __builtin_amdgcn_mfma_f32_16x16x32_bf16(d[i][1], w, acc1, 0, 0, 0);
            acc2 = __builtin_amdgcn_mfma_f32_16x16x32_bf16(d[i][2], w, acc2, 0, 0, 0);
            acc3 = __builtin_amdgcn_mfma_f32_16x16x32_bf16(d[i][3], w, acc3, 0, 0, 0);
          }
        }
      }
    }
    __syncthreads();   // A: h0stage complete; red[0..3] complete

    // ============ L0 epilogue (waves 0-3) overlaps part 2 (waves 4-7) ============
    if (run0 && tid < 256) {
      int b = tid >> 2;
      const float* rr = red + b * 16 + (tid & 3) * 4;
      float4v v = *(const float4v*)rr;
      v += *(const float4v*)(rr + 1024);
      v += *(const float4v*)(rr + 2048);
      v += *(const float4v*)(rr + 3072);
      float ig = sigm(v.x + bs0);
      float gg = tanhf(v.y + bs1);
      float fg = sigm(v.z + bs2);
      float og = sigm(v.w + bs3);
      float c = fg * cstr + ig * gg;
      cstr = c;
      unsigned x  = f2bf(og * tanhf(c));
      unsigned x1 = (unsigned)__shfl((int)x, lane + 1);
      unsigned x2 = (unsigned)__shfl((int)x, lane + 2);
      unsigned x3 = (unsigned)__shfl((int)x, lane + 3);
      if ((lane & 3) == 0) {
        ull val = (ull)(x | (x1 << 16)) | ((ull)(x2 | (x3 << 16)) << 32);
        ushort* dst = h0buf + (size_t)((p & 1) ^ 1) * BH
                    + ((wg >> 3) << 11) + b * 32 + (wg & 7) * 4;
        __hip_atomic_store((ull*)dst, val, __ATOMIC_RELAXED, __HIP_MEMORY_SCOPE_AGENT);
      }
    }
    if (run1 && wv >= 4) {   // part 2: h0c half (8 blocks, LDS when staged)
      const ushort* h0c = h0buf + (size_t)(p & 1) * BH;          // h0(p-1) tiled
      const bool useLds = (p < SEQL);    // at p==SEQL L0 didn't stage
      #pragma unroll
      for (int bb = 0; bb < 2; ++bb) {
        short8 d[4][4];
        #pragma unroll
        for (int i = 0; i < 4; ++i) {
          int kb = (wv - 4) * 8 + bb * 4 + i;
          if (useLds && kb <= 30) {
            const ushort* sp = h0st + kb * 2048 + lofs;
            d[i][0] = *(const short8*)(sp);
            d[i][1] = *(const short8*)(sp + 512);
            d[i][2] = *(const short8*)(sp + 1024);
            d[i][3] = *(const short8*)(sp + 1536);
          } else {
            const ushort* ab = h0c + kb * 2048 + lofs;
            d[i][0] = *(const short8*)(ab);
            d[i][1] = *(const short8*)(ab + 512);
            d[i][2] = *(const short8*)(ab + 1024);
            d[i][3] = *(const short8*)(ab + 1536);
          }
        }
        #pragma unroll
        for (int i = 0; i < 4; ++i) {
          short8 w = bfr[8 + bb * 4 + i];
          acc0 = __builtin_amdgcn_mfma_f32_16x16x32_bf16(d[i][0], w, acc0, 0, 0, 0);
          acc1 = __builtin_amdgcn_mfma_f32_16x16x32_bf16(d[i][1], w, acc1, 0, 0, 0);
          acc2 = __builtin_amdgcn_mfma_f32_16x16x32_bf16(d[i][2], w, acc2, 0, 0, 0);
          acc3 = __builtin_amdgcn_mfma_f32_16x16x32_bf16(d[i][3], w, acc3, 0, 0, 0);
        }
      }
      float* rw = red + wv * 1024 + quad * 64 + l15;
      #pragma unroll
      for (int r = 0; r < 4; ++r) {
        rw[r * 16]       = acc0[r];
        rw[256 + r * 16] = acc1[r];
        rw[512 + r * 16] = acc2[r];
        rw[768 + r * 16] = acc3[r];
      }
    }
    __syncthreads();   // B: red[4..7] complete

    if (run1 && tid >= 256) {   // L1 epilogue
      int t = tid - 256, b = t >> 2;
      const float* rr = red + 4096 + b * 16 + (t & 3) * 4;
      float4v v = *(const float4v*)rr;
      v += *(const float4v*)(rr + 1024);
      v += *(const float4v*)(rr + 2048);
      v += *(const float4v*)(rr + 3072);
      float ig = sigm(v.x + bs0);
      float gg = tanhf(v.y + bs1);
      float fg = sigm(v.z + bs2);
      float og = sigm(v.w + bs3);
      float c = fg * cstr + ig * gg;
      cstr = c;
      unsigned x  = f2bf(og * tanhf(c));
      unsigned x1 = (unsigned)__shfl((int)x, lane + 1);
      unsigned x2 = (unsigned)__shfl((int)x, lane + 2);
      unsigned x3 = (unsigned)__shfl((int)x, lane + 3);
      if ((lane & 3) == 0) {
        ull val = (ull)(x | (x1 << 16)) | ((ull)(x2 | (x3 << 16)) << 32);
        ushort* dst = h1buf + (size_t)(p & 1) * BH
                    + ((wg >> 3) << 11) + b * 32 + (wg & 7) * 4;
        __hip_atomic_store((ull*)dst, val, __ATOMIC_RELAXED, __HIP_MEMORY_SCOPE_AGENT);
      }
    }
    if (p == SEQL) break;          // final h1(255) published (buf 0); done
    hbar(ctr, xcc, nloc, nxcd, ++tgt);
  }
}

// logits via MFMA: out[b][n] = sum_k h1[b][k] * Wout[k][n] + bout[n]
__global__ __launch_bounds__(256, 1)
void out_gemm_k(const char* __restrict__ ws, const float* __restrict__ Wout,
                const float* __restrict__ bout, float* __restrict__ out) {
  const ushort* h1 = (const ushort*)(ws + WS_H1G);  // bf16 tiled, buf 0
  const int tid = threadIdx.x, lane = tid & 63, wv = tid >> 6;
  const int l15 = lane & 15, quad = lane >> 4;
  const int n0 = blockIdx.x * 128 + wv * 32;
  float4v acc[4][2];
  #pragma unroll
  for (int m = 0; m < 4; ++m)
    #pragma unroll
    for (int f = 0; f < 2; ++f) acc[m][f] = (float4v){0.f, 0.f, 0.f, 0.f};

  for (int k0 = 0; k0 < HIDD; k0 += 32) {
    const ushort* tb = h1 + ((k0 >> 5) << 11) + l15 * 32 + quad * 8;
    short8 a[4];
    #pragma unroll
    for (int m = 0; m < 4; ++m)
      a[m] = *(const short8*)(tb + m * 512);
    short8 bf[2];
    #pragma unroll
    for (int f = 0; f < 2; ++f) {
      int n = n0 + f * 16 + l15;
      #pragma unroll
      for (int j = 0; j < 8; ++j) {
        float w = Wout[(size_t)(k0 + quad * 8 + j) * NCLS + n];
        bf[f][j] = (short)f2bf(w);
      }
    }
    #pragma unroll
    for (int m = 0; m < 4; ++m)
      #pragma unroll
      for (int f = 0; f < 2; ++f)
        acc[m][f] = __builtin_amdgcn_mfma_f32_16x16x32_bf16(a[m], bf[f], acc[m][f], 0, 0, 0);
  }
  #pragma unroll
  for (int m = 0; m < 4; ++m)
    #pragma unroll
    for (int f = 0; f < 2; ++f) {
      int n = n0 + f * 16 + l15;
      float bb = bout[n];
      #pragma unroll
      for (int r = 0; r < 4; ++r) {
        int b = m * 16 + quad * 4 + r;
        out[(size_t)b * NCLS + n] = acc[m][f][r] + bb;
      }
    }
}

extern "C" void kernel_launch(void* const* d_in, const int* in_sizes, int n_in,
                              void* d_out, int out_size, void* d_ws, size_t ws_size,
                              hipStream_t stream) {
  const int*   X    = (const int*)d_in[0];
  const float* Cemb = (const float*)d_in[1];
  const float* Wi0  = (const float*)d_in[2];
  const float* bi0  = (const float*)d_in[3];
  const float* Wc0  = (const float*)d_in[4];
  const float* bc0  = (const float*)d_in[5];
  const float* Wf0  = (const float*)d_in[6];
  const float* bf0  = (const float*)d_in[7];
  const float* Wo0  = (const float*)d_in[8];
  const float* bo0  = (const float*)d_in[9];
  const float* Wi1  = (const float*)d_in[10];
  const float* bi1  = (const float*)d_in[11];
  const float* Wc1  = (const float*)d_in[12];
  const float* bc1  = (const float*)d_in[13];
  const float* Wf1  = (const float*)d_in[14];
  const float* bf1  = (const float*)d_in[15];
  const float* Wo1  = (const float*)d_in[16];
  const float* bo1  = (const float*)d_in[17];
  const float* Wout = (const float*)d_in[18];
  const float* bout = (const float*)d_in[19];
  float* out = (float*)d_out;
  char* ws = (char*)d_ws;

  hipFuncSetAttribute((const void*)lstm_k,
                      hipFuncAttributeMaxDynamicSharedMemorySize, SMEM_BYTES);

  init_bar_k<<<1, 512, 0, stream>>>(ws);
  embed_k<<<16384, 256, 0, stream>>>(X, Cemb, ws);
  lstm_k<<<NWG, 512, SMEM_BYTES, stream>>>(Wi0, Wc0, Wf0, Wo0, Wi1, Wc1, Wf1, Wo1,
                                           bi0, bc0, bf0, bo0, bi1, bc1, bf1, bo1, ws);
  out_gemm_k<<<250, 256, 0, stream>>>(ws, Wout, bout, out);
}

// Round 9
// 2795.136 us; speedup vs baseline: 1.6606x; 1.0121x over previous
//
#include <hip/hip_runtime.h>
#include <cstdint>
#include <cstddef>

#define NCLS 32000
#define EMBD 512
#define HIDD 1024
#define BATCH 64
#define SEQL 256
#define NWG 256
#define BH (BATCH * HIDD)          // 65536 elements
#define HBYTES (BH * 2)            // 131072 bytes per h buffer

// ---- tiled layout: buf[k/32][64 b][32 k] bf16 (4KB tiles, k-contiguous rows of 64B)
// element (b,k) -> (k>>5)*2048 + b*32 + (k&31)

typedef __attribute__((ext_vector_type(8))) short short8;
typedef __attribute__((ext_vector_type(4))) float float4v;
typedef unsigned long long ull;
typedef unsigned short ushort;

// ---- workspace layout (bytes) ----
#define WS_CTR   0                           // 2048 B reserved
#define WS_H0G   2048                        // 2 buffers bf16 tiled
#define WS_H1G   (WS_H0G + 2*HBYTES)
#define WS_XEMB  (WS_H1G + 2*HBYTES)         // 16 MB, tiled per t

// ---- LDS: h0stage [31 blocks][2048 ushort] = 126976 B | red [8][64][16] f32 = 32768 B | meta 16 B
#define LDS_RED_OFF  126976
#define LDS_META_OFF (126976 + 32768)
#define SMEM_BYTES   (126976 + 32768 + 16)

__device__ __forceinline__ ushort f2bf(float f) {
  union { float f; uint32_t u; } x; x.f = f;
  uint32_t r = x.u + 0x7FFFu + ((x.u >> 16) & 1u);
  return (ushort)(r >> 16);
}

__device__ __forceinline__ float sigm(float x) {
  return 1.0f / (1.0f + __expf(-x));
}

// flat monotonic barrier (startup only) with deadlock watchdog
__device__ __forceinline__ void gbar(unsigned* bar, unsigned* gen, unsigned* dead,
                                     unsigned target) {
  __syncthreads();
  if (threadIdx.x == 0) {
    unsigned prev = __hip_atomic_fetch_add(bar, 1u, __ATOMIC_RELAXED, __HIP_MEMORY_SCOPE_AGENT);
    if (prev == target * NWG - 1u) {
      __hip_atomic_store(gen, target, __ATOMIC_RELAXED, __HIP_MEMORY_SCOPE_AGENT);
    } else {
      unsigned spin = 0;
      while (__hip_atomic_load(gen, __ATOMIC_RELAXED, __HIP_MEMORY_SCOPE_AGENT) < target) {
        if (__hip_atomic_load(dead, __ATOMIC_RELAXED, __HIP_MEMORY_SCOPE_AGENT) != 0u) break;
        if (++spin > 2000000u) {
          __hip_atomic_store(dead, 1u, __ATOMIC_RELAXED, __HIP_MEMORY_SCOPE_AGENT);
          break;
        }
        __builtin_amdgcn_s_sleep(1);
      }
    }
  }
  __syncthreads();
}

// hierarchical monotonic barrier: per-XCD aggregation; buffer_inv issued by the
// XCD-last-arriver BEFORE the global release wait (overlaps the fan-in).
__device__ __forceinline__ void hbar(unsigned* ctr, unsigned xcc, unsigned nloc,
                                     unsigned nxcd, unsigned tgt) {
  __syncthreads();   // drains vmcnt -> this WG's publishes are acked
  if (threadIdx.x == 0) {
    unsigned* xctr = ctr + 64 + 16 * xcc;
    unsigned* xgen = ctr + 192 + 16 * xcc;
    unsigned* dead = ctr + 17;
    unsigned a = __hip_atomic_fetch_add(xctr, 1u, __ATOMIC_RELAXED, __HIP_MEMORY_SCOPE_AGENT);
    if (a == tgt * nloc - 1u) {            // last arriver on this XCD
      asm volatile("buffer_inv sc1\n\ts_waitcnt vmcnt(0)" ::: "memory");
      unsigned g = __hip_atomic_fetch_add(ctr, 1u, __ATOMIC_RELAXED, __HIP_MEMORY_SCOPE_AGENT);
      if (g == tgt * nxcd - 1u) {          // last arriver globally
        __hip_atomic_store(ctr + 16, tgt, __ATOMIC_RELAXED, __HIP_MEMORY_SCOPE_AGENT);
      } else {
        unsigned spin = 0;
        while (__hip_atomic_load(ctr + 16, __ATOMIC_RELAXED, __HIP_MEMORY_SCOPE_AGENT) < tgt) {
          if ((++spin & 63u) == 0u) {
            if (__hip_atomic_load(dead, __ATOMIC_RELAXED, __HIP_MEMORY_SCOPE_AGENT) != 0u) break;
            if (spin > 4000000u) {
              __hip_atomic_store(dead, 1u, __ATOMIC_RELAXED, __HIP_MEMORY_SCOPE_AGENT);
              break;
            }
          }
        }
      }
      __hip_atomic_store(xgen, tgt, __ATOMIC_RELAXED, __HIP_MEMORY_SCOPE_AGENT);
    } else {
      unsigned spin = 0;
      while (__hip_atomic_load(xgen, __ATOMIC_RELAXED, __HIP_MEMORY_SCOPE_AGENT) < tgt) {
        if ((++spin & 63u) == 0u) {
          if (__hip_atomic_load(dead, __ATOMIC_RELAXED, __HIP_MEMORY_SCOPE_AGENT) != 0u) break;
          if (spin > 4000000u) {
            __hip_atomic_store(dead, 1u, __ATOMIC_RELAXED, __HIP_MEMORY_SCOPE_AGENT);
            break;
          }
        }
      }
    }
  }
  __syncthreads();
}

__global__ void init_bar_k(char* ws) {
  if (threadIdx.x < 320) ((unsigned*)(ws + WS_CTR))[threadIdx.x] = 0u;
}

// gather embeddings -> bf16 xemb, tiled [t][e/32][64 b][32 e]
__global__ void embed_k(const int* __restrict__ X, const float* __restrict__ Cemb,
                        char* __restrict__ ws) {
  uint32_t p = blockIdx.x * 256u + threadIdx.x;   // pair index, 256*64*256 = 4194304
  uint32_t t = p >> 14;
  uint32_t r = p & 16383u;
  uint32_t b = r >> 8;
  uint32_t e2 = r & 255u;                         // pair index within row (e = 2*e2)
  int row = X[b * SEQL + t];
  const float2 v = *(const float2*)(Cemb + (size_t)row * EMBD + (size_t)e2 * 2);
  uint32_t lo = f2bf(v.x), hi = f2bf(v.y);
  uint32_t dw = t * 16384u + (e2 >> 4) * 1024u + b * 16u + (e2 & 15u);
  ((uint32_t*)(ws + WS_XEMB))[dw] = (hi << 16) | lo;
}

__global__ __launch_bounds__(512, 1)
void lstm_k(const float* __restrict__ Wi0, const float* __restrict__ Wc0,
            const float* __restrict__ Wf0, const float* __restrict__ Wo0,
            const float* __restrict__ Wi1, const float* __restrict__ Wc1,
            const float* __restrict__ Wf1, const float* __restrict__ Wo1,
            const float* __restrict__ bi0, const float* __restrict__ bc0,
            const float* __restrict__ bf0, const float* __restrict__ bo0,
            const float* __restrict__ bi1, const float* __restrict__ bc1,
            const float* __restrict__ bf1, const float* __restrict__ bo1,
            char* ws) {
  const int wg   = blockIdx.x;
  const int tid  = threadIdx.x;
  const int lane = tid & 63;
  const int wv   = tid >> 6;        // 0..7
  const int l15  = lane & 15;
  const int quad = lane >> 4;

  extern __shared__ char smem[];
  ushort* h0st = (ushort*)smem;                       // [31][2048] fragment-layout h0 stage
  float*  red  = (float*)(smem + LDS_RED_OFF);        // [8 waves][64 b][16 n]
  int*    meta = (int*)(smem + LDS_META_OFF);         // [0]=nloc, [1]=nxcd

  ushort* h0buf = (ushort*)(ws + WS_H0G);
  ushort* h1buf = (ushort*)(ws + WS_H1G);
  const ushort* xemb = (const ushort*)(ws + WS_XEMB);
  unsigned* ctr = (unsigned*)(ws + WS_CTR);

  // XCD id (HW_REG_XCC_ID = hwreg 20, offset 0, width 4) [measured: learn_hip m09]
  const unsigned xcc = __builtin_amdgcn_s_getreg((3u << 11) | 20u) & 7u;

  if (tid == 0)
    __hip_atomic_fetch_add(ctr + 32 + xcc, 1u, __ATOMIC_RELAXED, __HIP_MEMORY_SCOPE_AGENT);

  // ---- weight fragments -> VGPRs via LDS bounce (one-time) ----
  // B-fragment for n-rows [16] (= 4 units x 4 gates), per-wave private K-slices.
  short8 bfr[16];
  {
    ushort* scr = (ushort*)smem;     // scratch overlaps h0stage (pre-loop only)
    // stage w0 rows [16][1536]
    {
      const float* W0g[4] = {Wi0, Wc0, Wf0, Wo0};
      int jl = tid & 3, kr = tid >> 2, jg = wg * 4 + jl;
      for (int g = 0; g < 4; ++g) {
        ushort* dst = scr + (jl * 4 + g) * 1536;
        const float* s = W0g[g] + jg;
        for (int k = kr; k < 1536; k += 128) dst[k] = f2bf(s[(size_t)k * HIDD]);
      }
    }
    __syncthreads();
    if (wv < 4) {
      #pragma unroll
      for (int j = 0; j < 12; ++j)
        bfr[j] = *(const short8*)(scr + l15 * 1536 + (12 * wv + j) * 32 + quad * 8);
    }
    __syncthreads();
    // stage w1 rows [16][2048]
    {
      const float* W1g[4] = {Wi1, Wc1, Wf1, Wo1};
      int jl = tid & 3, kr = tid >> 2, jg = wg * 4 + jl;
      for (int g = 0; g < 4; ++g) {
        ushort* dst = scr + (jl * 4 + g) * 2048;
        const float* s = W1g[g] + jg;
        for (int k = kr; k < 2048; k += 128) dst[k] = f2bf(s[(size_t)k * HIDD]);
      }
    }
    __syncthreads();
    if (wv >= 4) {
      #pragma unroll
      for (int j = 0; j < 8; ++j)   // h1p slice
        bfr[j] = *(const short8*)(scr + l15 * 2048 + ((wv - 4) * 256 + j * 32) + quad * 8);
      #pragma unroll
      for (int j = 0; j < 8; ++j)   // h0c slice
        bfr[8 + j] = *(const short8*)(scr + l15 * 2048 + 1024 + ((wv - 4) * 256 + j * 32) + quad * 8);
    }
    __syncthreads();
  }

  // ---- per-epilogue-thread bias + c-state in registers ----
  float bs0 = 0.f, bs1 = 0.f, bs2 = 0.f, bs3 = 0.f, cstr = 0.f;
  {
    int jl = tid & 3, jg = wg * 4 + jl;
    if (tid < 256) { bs0 = bi0[jg]; bs1 = bc0[jg]; bs2 = bf0[jg]; bs3 = bo0[jg]; }
    else           { bs0 = bi1[jg]; bs1 = bc1[jg]; bs2 = bf1[jg]; bs3 = bo1[jg]; }
  }

  if (tid < 128) {   // zero h state (buffer 0), tiled addressing
    ushort* base = (tid < 64) ? h0buf : h1buf;
    int b = tid & 63;
    __hip_atomic_store((ull*)(base + ((wg >> 3) << 11) + b * 32 + (wg & 7) * 4), 0ull,
                       __ATOMIC_RELAXED, __HIP_MEMORY_SCOPE_AGENT);
  }

  gbar(ctr + 48, ctr + 56, ctr + 17, 1u);   // startup: membership final, h zeroed, weights ready

  if (tid == 0) {
    int nl = (int)__hip_atomic_load(ctr + 32 + xcc, __ATOMIC_RELAXED, __HIP_MEMORY_SCOPE_AGENT);
    int nx = 0;
    for (int x = 0; x < 8; ++x)
      nx += (__hip_atomic_load(ctr + 32 + x, __ATOMIC_RELAXED, __HIP_MEMORY_SCOPE_AGENT) != 0u);
    meta[0] = nl; meta[1] = nx;
  }
  __syncthreads();
  const unsigned nloc = (unsigned)meta[0], nxcd = (unsigned)meta[1];

  const int lofs = l15 * 32 + quad * 8;            // per-lane offset within a 2048-elem tile
  // XOR-swizzled stage offset: spreads each 16-lane quarter across all 8 16B
  // slot-groups per 128B bank row (was 8-way conflict at 64B stride). Injective
  // over (l15,quad); readers use the identical lane-local formula.
  const int lswz = lofs ^ ((l15 & 7) * 8);

  unsigned tgt = 0;
  // phase p: part1 {L0 full (+h0 LDS staging) | L1 h1p half} -> syncA ->
  //          {L0 epilogue || L1 h0c half from LDS} -> syncB -> L1 epilogue -> hbar
  for (int p = 0; p <= SEQL; ++p) {
    const int run0 = (p < SEQL);
    const int run1 = (p >= 1);
    float4v acc0 = {0.f,0.f,0.f,0.f}, acc1 = acc0, acc2 = acc0, acc3 = acc0;

    // ================= part 1 =================
    if (wv < 4) {
      if (run0) {
        const ushort* hp = h0buf + (size_t)(p & 1) * BH;        // h0(p-1) tiled
        const ushort* xe = xemb + (size_t)p * BATCH * EMBD;     // x(p) tiled
        #pragma unroll
        for (int bb = 0; bb < 2; ++bb) {
          short8 d[6][4];
          #pragma unroll
          for (int i = 0; i < 6; ++i) {
            int kb = 12 * wv + bb * 6 + i;
            const ushort* base = (kb < 32) ? (hp + kb * 2048) : (xe + (kb - 32) * 2048);
            const ushort* ab = base + lofs;
            d[i][0] = *(const short8*)(ab);
            d[i][1] = *(const short8*)(ab + 512);
            d[i][2] = *(const short8*)(ab + 1024);
            d[i][3] = *(const short8*)(ab + 1536);
          }
          #pragma unroll
          for (int i = 0; i < 6; ++i) {
            int kb = 12 * wv + bb * 6 + i;
            if (kb <= 30) {           // stage h0 fragment for L1's h0c pass (swizzled)
              ushort* sp = h0st + kb * 2048 + lswz;
              *(short8*)(sp)        = d[i][0];
              *(short8*)(sp + 512)  = d[i][1];
              *(short8*)(sp + 1024) = d[i][2];
              *(short8*)(sp + 1536) = d[i][3];
            }
            short8 w = bfr[bb * 6 + i];
            acc0 = __builtin_amdgcn_mfma_f32_16x16x32_bf16(d[i][0], w, acc0, 0, 0, 0);
            acc1 = __builtin_amdgcn_mfma_f32_16x16x32_bf16(d[i][1], w, acc1, 0, 0, 0);
            acc2 = __builtin_amdgcn_mfma_f32_16x16x32_bf16(d[i][2], w, acc2, 0, 0, 0);
            acc3 = __builtin_amdgcn_mfma_f32_16x16x32_bf16(d[i][3], w, acc3, 0, 0, 0);
          }
        }
        float* rw = red + wv * 1024 + quad * 64 + l15;
        #pragma unroll
        for (int r = 0; r < 4; ++r) {
          rw[r * 16]       = acc0[r];
          rw[256 + r * 16] = acc1[r];
          rw[512 + r * 16] = acc2[r];
          rw[768 + r * 16] = acc3[r];
        }
      }
    } else {
      if (run1) {   // h1p half (8 blocks, global)
        const ushort* h1p = h1buf + (size_t)((p & 1) ^ 1) * BH;  // h1(p-2) tiled
        #pragma unroll
        for (int bb = 0; bb < 2; ++bb) {
          short8 d[4][4];
          #pragma unroll
          for (int i = 0; i < 4; ++i) {
            int kb = (wv - 4) * 8 + bb * 4 + i;
            const ushort* ab = h1p + kb * 2048 + lofs;
            d[i][0] = *(const short8*)(ab);
            d[i][1] = *(const short8*)(ab + 512);
            d[i][2] = *(const short8*)(ab + 1024);
            d[i][3] = *(const short8*)(ab + 1536);
          }
          #pragma unroll
          for (int i = 0; i < 4; ++i) {
            short8 w = bfr[bb * 4 + i];
            acc0 = __builtin_amdgcn_mfma_f32_16x16x32_bf16(d[i][0], w, acc0, 0, 0, 0);
            acc1 = __builtin_amdgcn_mfma_f32_16x16x32_bf16(d[i][1], w, acc1, 0, 0, 0);
            acc2 = __builtin_amdgcn_mfma_f32_16x16x32_bf16(d[i][2], w, acc2, 0, 0, 0);
            acc3 = __builtin_amdgcn_mfma_f32_16x16x32_bf16(d[i][3], w, acc3, 0, 0, 0);
          }
        }
      }
    }
    __syncthreads();   // A: h0stage complete; red[0..3] complete

    // ============ L0 epilogue (waves 0-3) overlaps part 2 (waves 4-7) ============
    if (run0 && tid < 256) {
      int b = tid >> 2;
      const float* rr = red + b * 16 + (tid & 3) * 4;
      float4v v = *(const float4v*)rr;
      v += *(const float4v*)(rr + 1024);
      v += *(const float4v*)(rr + 2048);
      v += *(const float4v*)(rr + 3072);
      float ig = sigm(v.x + bs0);
      float gg = tanhf(v.y + bs1);
      float fg = sigm(v.z + bs2);
      float og = sigm(v.w + bs3);
      float c = fg * cstr + ig * gg;
      cstr = c;
      unsigned x  = f2bf(og * tanhf(c));
      unsigned x1 = (unsigned)__shfl((int)x, lane + 1);
      unsigned x2 = (unsigned)__shfl((int)x, lane + 2);
      unsigned x3 = (unsigned)__shfl((int)x, lane + 3);
      if ((lane & 3) == 0) {
        ull val = (ull)(x | (x1 << 16)) | ((ull)(x2 | (x3 << 16)) << 32);
        ushort* dst = h0buf + (size_t)((p & 1) ^ 1) * BH
                    + ((wg >> 3) << 11) + b * 32 + (wg & 7) * 4;
        __hip_atomic_store((ull*)dst, val, __ATOMIC_RELAXED, __HIP_MEMORY_SCOPE_AGENT);
      }
    }
    if (run1 && wv >= 4) {   // part 2: h0c half (8 blocks, LDS when staged)
      const ushort* h0c = h0buf + (size_t)(p & 1) * BH;          // h0(p-1) tiled
      const bool useLds = (p < SEQL);    // at p==SEQL L0 didn't stage
      #pragma unroll
      for (int bb = 0; bb < 2; ++bb) {
        short8 d[4][4];
        #pragma unroll
        for (int i = 0; i < 4; ++i) {
          int kb = (wv - 4) * 8 + bb * 4 + i;
          if (useLds && kb <= 30) {
            const ushort* sp = h0st + kb * 2048 + lswz;
            d[i][0] = *(const short8*)(sp);
            d[i][1] = *(const short8*)(sp + 512);
            d[i][2] = *(const short8*)(sp + 1024);
            d[i][3] = *(const short8*)(sp + 1536);
          } else {
            const ushort* ab = h0c + kb * 2048 + lofs;
            d[i][0] = *(const short8*)(ab);
            d[i][1] = *(const short8*)(ab + 512);
            d[i][2] = *(const short8*)(ab + 1024);
            d[i][3] = *(const short8*)(ab + 1536);
          }
        }
        #pragma unroll
        for (int i = 0; i < 4; ++i) {
          short8 w = bfr[8 + bb * 4 + i];
          acc0 = __builtin_amdgcn_mfma_f32_16x16x32_bf16(d[i][0], w, acc0, 0, 0, 0);
          acc1 = __builtin_amdgcn_mfma_f32_16x16x32_bf16(d[i][1], w, acc1, 0, 0, 0);
          acc2 = __builtin_amdgcn_mfma_f32_16x16x32_bf16(d[i][2], w, acc2, 0, 0, 0);
          acc3 = __builtin_amdgcn_mfma_f32_16x16x32_bf16(d[i][3], w, acc3, 0, 0, 0);
        }
      }
      float* rw = red + wv * 1024 + quad * 64 + l15;
      #pragma unroll
      for (int r = 0; r < 4; ++r) {
        rw[r * 16]       = acc0[r];
        rw[256 + r * 16] = acc1[r];
        rw[512 + r * 16] = acc2[r];
        rw[768 + r * 16] = acc3[r];
      }
    }
    __syncthreads();   // B: red[4..7] complete

    if (run1 && tid >= 256) {   // L1 epilogue
      int t = tid - 256, b = t >> 2;
      const float* rr = red + 4096 + b * 16 + (t & 3) * 4;
      float4v v = *(const float4v*)rr;
      v += *(const float4v*)(rr + 1024);
      v += *(const float4v*)(rr + 2048);
      v += *(const float4v*)(rr + 3072);
      float ig = sigm(v.x + bs0);
      float gg = tanhf(v.y + bs1);
      float fg = sigm(v.z + bs2);
      float og = sigm(v.w + bs3);
      float c = fg * cstr + ig * gg;
      cstr = c;
      unsigned x  = f2bf(og * tanhf(c));
      unsigned x1 = (unsigned)__shfl((int)x, lane + 1);
      unsigned x2 = (unsigned)__shfl((int)x, lane + 2);
      unsigned x3 = (unsigned)__shfl((int)x, lane + 3);
      if ((lane & 3) == 0) {
        ull val = (ull)(x | (x1 << 16)) | ((ull)(x2 | (x3 << 16)) << 32);
        ushort* dst = h1buf + (size_t)(p & 1) * BH
                    + ((wg >> 3) << 11) + b * 32 + (wg & 7) * 4;
        __hip_atomic_store((ull*)dst, val, __ATOMIC_RELAXED, __HIP_MEMORY_SCOPE_AGENT);
      }
    }
    if (p == SEQL) break;          // final h1(255) published (buf 0); done
    hbar(ctr, xcc, nloc, nxcd, ++tgt);
  }
}

// logits via MFMA: out[b][n] = sum_k h1[b][k] * Wout[k][n] + bout[n]
__global__ __launch_bounds__(256, 1)
void out_gemm_k(const char* __restrict__ ws, const float* __restrict__ Wout,
                const float* __restrict__ bout, float* __restrict__ out) {
  const ushort* h1 = (const ushort*)(ws + WS_H1G);  // bf16 tiled, buf 0
  const int tid = threadIdx.x, lane = tid & 63, wv = tid >> 6;
  const int l15 = lane & 15, quad = lane >> 4;
  const int n0 = blockIdx.x * 128 + wv * 32;
  float4v acc[4][2];
  #pragma unroll
  for (int m = 0; m < 4; ++m)
    #pragma unroll
    for (int f = 0; f < 2; ++f) acc[m][f] = (float4v){0.f, 0.f, 0.f, 0.f};

  for (int k0 = 0; k0 < HIDD; k0 += 32) {
    const ushort* tb = h1 + ((k0 >> 5) << 11) + l15 * 32 + quad * 8;
    short8 a[4];
    #pragma unroll
    for (int m = 0; m < 4; ++m)
      a[m] = *(const short8*)(tb + m * 512);
    short8 bf[2];
    #pragma unroll
    for (int f = 0; f < 2; ++f) {
      int n = n0 + f * 16 + l15;
      #pragma unroll
      for (int j = 0; j < 8; ++j) {
        float w = Wout[(size_t)(k0 + quad * 8 + j) * NCLS + n];
        bf[f][j] = (short)f2bf(w);
      }
    }
    #pragma unroll
    for (int m = 0; m < 4; ++m)
      #pragma unroll
      for (int f = 0; f < 2; ++f)
        acc[m][f] = __builtin_amdgcn_mfma_f32_16x16x32_bf16(a[m], bf[f], acc[m][f], 0, 0, 0);
  }
  #pragma unroll
  for (int m = 0; m < 4; ++m)
    #pragma unroll
    for (int f = 0; f < 2; ++f) {
      int n = n0 + f * 16 + l15;
      float bb = bout[n];
      #pragma unroll
      for (int r = 0; r < 4; ++r) {
        int b = m * 16 + quad * 4 + r;
        out[(size_t)b * NCLS + n] = acc[m][f][r] + bb;
      }
    }
}

extern "C" void kernel_launch(void* const* d_in, const int* in_sizes, int n_in,
                              void* d_out, int out_size, void* d_ws, size_t ws_size,
                              hipStream_t stream) {
  const int*   X    = (const int*)d_in[0];
  const float* Cemb = (const float*)d_in[1];
  const float* Wi0  = (const float*)d_in[2];
  const float* bi0  = (const float*)d_in[3];
  const float* Wc0  = (const float*)d_in[4];
  const float* bc0  = (const float*)d_in[5];
  const float* Wf0  = (const float*)d_in[6];
  const float* bf0  = (const float*)d_in[7];
  const float* Wo0  = (const float*)d_in[8];
  const float* bo0  = (const float*)d_in[9];
  const float* Wi1  = (const float*)d_in[10];
  const float* bi1  = (const float*)d_in[11];
  const float* Wc1  = (const float*)d_in[12];
  const float* bc1  = (const float*)d_in[13];
  const float* Wf1  = (const float*)d_in[14];
  const float* bf1  = (const float*)d_in[15];
  const float* Wo1  = (const float*)d_in[16];
  const float* bo1  = (const float*)d_in[17];
  const float* Wout = (const float*)d_in[18];
  const float* bout = (const float*)d_in[19];
  float* out = (float*)d_out;
  char* ws = (char*)d_ws;

  hipFuncSetAttribute((const void*)lstm_k,
                      hipFuncAttributeMaxDynamicSharedMemorySize, SMEM_BYTES);

  init_bar_k<<<1, 512, 0, stream>>>(ws);
  embed_k<<<16384, 256, 0, stream>>>(X, Cemb, ws);
  lstm_k<<<NWG, 512, SMEM_BYTES, stream>>>(Wi0, Wc0, Wf0, Wo0, Wi1, Wc1, Wf1, Wo1,
                                           bi0, bc0, bf0, bo0, bi1, bc1, bf1, bo1, ws);
  out_gemm_k<<<250, 256, 0, stream>>>(ws, Wout, bout, out);
}